// Round 4
// baseline (4351.166 us; speedup 1.0000x reference)
//
#include <hip/hip_runtime.h>
#include <math.h>

#define NATOM 50000
#define NEDGE 800000
#define NGRAPH 256
#define HD 128
#define NL 4
#define AFD 108
#define EFD 41
#define GFD 239
#define TOUT 5
#define LNEPS 1e-5f

typedef __attribute__((ext_vector_type(8))) short short8;
typedef __attribute__((ext_vector_type(4))) float f32x4;

__device__ __forceinline__ float silu_f(float v) { return v / (1.f + __expf(-v)); }

__device__ __forceinline__ unsigned short f2b(float f) {
    union { float f; unsigned u; } x; x.f = f;
    unsigned r = x.u + 0x7fffu + ((x.u >> 16) & 1u);   // RNE
    return (unsigned short)(r >> 16);
}

// ---------------- CSR build: histogram of dst ----------------
__global__ void hist_kernel(const int* __restrict__ dst, int* __restrict__ count) {
    for (int e = blockIdx.x * blockDim.x + threadIdx.x; e < NEDGE; e += gridDim.x * blockDim.x)
        atomicAdd(&count[dst[e]], 1);
}

__global__ void scan_kernel(const int* __restrict__ count, int* __restrict__ rowptr,
                            int* __restrict__ cursor) {
    __shared__ int s_w[4];
    __shared__ int s_carry;
    const int t = threadIdx.x, lane = t & 63, wv = t >> 6;
    if (t == 0) { s_carry = 0; rowptr[0] = 0; }
    __syncthreads();
    for (int base = 0; base < NATOM; base += 256) {
        int v = (base + t < NATOM) ? count[base + t] : 0;
        int x = v;
#pragma unroll
        for (int off = 1; off < 64; off <<= 1) {
            int y = __shfl_up(x, off);
            if (lane >= off) x += y;
        }
        if (lane == 63) s_w[wv] = x;
        __syncthreads();
        int wvoff = s_carry;
        for (int w = 0; w < wv; w++) wvoff += s_w[w];
        int incl = x + wvoff;
        if (base + t < NATOM) { rowptr[base + t + 1] = incl; cursor[base + t] = incl - v; }
        __syncthreads();
        if (t == 255) s_carry = incl;
        __syncthreads();
    }
}

__global__ void pos_kernel(const int* __restrict__ dst, int* __restrict__ cursor,
                           int* __restrict__ pos) {
    for (int e = blockIdx.x * blockDim.x + threadIdx.x; e < NEDGE; e += gridDim.x * blockDim.x) {
        int d = dst[e];
        pos[e] = atomicAdd(&cursor[d], 1);
    }
}

// ---- weight conversion: w1t[l][n][k<64] = bf16(ew1[l][k][n]) (k>=41 -> 0); w2t[l][n][k] = bf16(ew2[l][k][n]) ----
__global__ void wconv_kernel(const float* __restrict__ ew1, const float* __restrict__ ew2,
                             unsigned short* __restrict__ w1t, unsigned short* __restrict__ w2t) {
    int idx = blockIdx.x * 256 + threadIdx.x;
    const int n1 = NL * HD * 64;
    if (idx < n1) {
        int l = idx / (HD * 64); int rem = idx - l * HD * 64; int n = rem >> 6; int k = rem & 63;
        float v = (k < EFD) ? ew1[((size_t)l * EFD + k) * HD + n] : 0.f;
        w1t[idx] = f2b(v);
    } else {
        int j = idx - n1;
        if (j < NL * HD * HD) {
            int l = j / (HD * HD); int rem = j - l * HD * HD; int n = rem >> 7; int k = rem & 127;
            w2t[j] = f2b(ew2[((size_t)l * HD + k) * HD + n]);
        }
    }
}

// ---------------- atom embedding: h = silu(x@w1+b1)@w2 + b2 ----------------
__global__ __launch_bounds__(256, 2) void atom_kernel(
    const float* __restrict__ x, const float* __restrict__ w1, const float* __restrict__ b1,
    const float* __restrict__ w2, const float* __restrict__ b2, float* __restrict__ h)
{
    __shared__ float s_x[64 * AFD];
    __shared__ float s_hid[64 * HD];
    const int t = threadIdx.x, cg = t & 31, rg = t >> 5, c4 = cg * 4;
    const int r0 = blockIdx.x * 64;

    for (int i = t; i < 64 * AFD; i += 256) {
        size_t g = (size_t)r0 * AFD + i;
        s_x[i] = (g < (size_t)NATOM * AFD) ? x[g] : 0.f;
    }
    float4 bb1 = *(const float4*)&b1[c4];
    float4 bb2 = *(const float4*)&b2[c4];
    __syncthreads();

    float4 acc[8];
#pragma unroll
    for (int i = 0; i < 8; i++) acc[i] = bb1;
    for (int k = 0; k < AFD; k++) {
        float4 w = *(const float4*)&w1[k * HD + c4];
#pragma unroll
        for (int i = 0; i < 8; i++) {
            float a = s_x[(rg * 8 + i) * AFD + k];
            acc[i].x += a * w.x; acc[i].y += a * w.y; acc[i].z += a * w.z; acc[i].w += a * w.w;
        }
    }
#pragma unroll
    for (int i = 0; i < 8; i++) {
        float4 v = acc[i];
        v.x = silu_f(v.x); v.y = silu_f(v.y); v.z = silu_f(v.z); v.w = silu_f(v.w);
        *(float4*)&s_hid[(rg * 8 + i) * HD + c4] = v;
    }
    __syncthreads();

    float4 o[8];
#pragma unroll
    for (int i = 0; i < 8; i++) o[i] = bb2;
    for (int j = 0; j < HD; j++) {
        float4 w = *(const float4*)&w2[j * HD + c4];
#pragma unroll
        for (int i = 0; i < 8; i++) {
            float a = s_hid[(rg * 8 + i) * HD + j];
            o[i].x += a * w.x; o[i].y += a * w.y; o[i].z += a * w.z; o[i].w += a * w.w;
        }
    }
#pragma unroll
    for (int i = 0; i < 8; i++) {
        int r = r0 + rg * 8 + i;
        if (r < NATOM) *(float4*)&h[(size_t)r * HD + c4] = o[i];
    }
}

// -------- MFMA edge kernel: bf16 MFMA for both GEMMs, fp32 epilogue --------
// A-frag: lane l holds A[l&15][(l>>4)*8+j]; B-frag: B[(l>>4)*8+j][l&15]
// D: reg r -> D[(l>>4)*4+r][l&15]  (m89-verified C/D layout)
__global__ __launch_bounds__(256) void edge_kernel_mfma(
    const float* __restrict__ edge_attr,
    const unsigned short* __restrict__ w1t, const float* __restrict__ b1,
    const unsigned short* __restrict__ w2t, const float* __restrict__ b2,
    const int* __restrict__ src, const int* __restrict__ pos,
    const float* __restrict__ h, float* __restrict__ msg)
{
    __shared__ __align__(16) unsigned short s_a1[64 * 64];    // 8 KB, row = 128 B, XOR-swizzled
    __shared__ __align__(16) unsigned short s_hid[64 * 128];  // 16 KB, row = 256 B, XOR-swizzled
    __shared__ int s_src[64];
    __shared__ int s_pos[64];

    const int t = threadIdx.x;
    const int wv = t >> 6, lane = t & 63;
    const int lr = lane & 15, lk = lane >> 4;

    // zero-init s_a1 once: K-pad 41..63 stays zero forever (write/read sets coincide under swizzle)
    for (int i = t; i < 64 * 64; i += 256) s_a1[i] = 0;

    float b1v[8], b2v[8];
#pragma unroll
    for (int nt = 0; nt < 8; nt++) { b1v[nt] = b1[nt * 16 + lr]; b2v[nt] = b2[nt * 16 + lr]; }
    __syncthreads();

    const int ntiles = NEDGE / 64;
    for (int tile = blockIdx.x; tile < ntiles; tile += gridDim.x) {
        const int e0 = tile * 64;
        if (t < 64) { s_src[t] = src[e0 + t]; s_pos[t] = pos[e0 + t]; }
        // stage edge_attr -> bf16, swizzled
        for (int i = t; i < 64 * EFD; i += 256) {
            int e = i / EFD, k = i - e * EFD;
            float v = edge_attr[(size_t)e0 * EFD + i];
            int byte = e * 128 + ((2 * k) ^ ((e & 7) << 4));
            *(unsigned short*)((char*)s_a1 + byte) = f2b(v);
        }
        __syncthreads();

        // ---- GEMM1: hid[64,128] = silu(ea[64,64] @ w1[64,128]) ----
        short8 a0, a1;
        {
            int row = wv * 16 + lr;
            int sw = (row & 7) << 4;
            a0 = *(const short8*)((const char*)s_a1 + row * 128 + ((lk * 16) ^ sw));
            a1 = *(const short8*)((const char*)s_a1 + row * 128 + ((64 + lk * 16) ^ sw));
        }
        f32x4 acc[8];
#pragma unroll
        for (int nt = 0; nt < 8; nt++) {
            f32x4 c = {0.f, 0.f, 0.f, 0.f};
            short8 bf0 = *(const short8*)&w1t[(nt * 16 + lr) * 64 + lk * 8];
            short8 bf1 = *(const short8*)&w1t[(nt * 16 + lr) * 64 + 32 + lk * 8];
            c = __builtin_amdgcn_mfma_f32_16x16x32_bf16(a0, bf0, c, 0, 0, 0);
            c = __builtin_amdgcn_mfma_f32_16x16x32_bf16(a1, bf1, c, 0, 0, 0);
            acc[nt] = c;
        }
        // bias + silu -> bf16 -> s_hid (swizzled)
#pragma unroll
        for (int nt = 0; nt < 8; nt++) {
#pragma unroll
            for (int r = 0; r < 4; r++) {
                int row = wv * 16 + lk * 4 + r;
                int col = nt * 16 + lr;
                float v = silu_f(acc[nt][r] + b1v[nt]);
                int byte = row * 256 + ((2 * col) ^ ((row & 7) << 4));
                *(unsigned short*)((char*)s_hid + byte) = f2b(v);
            }
        }
        __syncthreads();

        // ---- GEMM2: o[64,128] = hid[64,128] @ w2[128,128] ----
        short8 ha[4];
        {
            int row = wv * 16 + lr;
            int sw = (row & 7) << 4;
#pragma unroll
            for (int kk = 0; kk < 4; kk++)
                ha[kk] = *(const short8*)((const char*)s_hid + row * 256 + ((kk * 64 + lk * 16) ^ sw));
        }
        f32x4 o[8];
#pragma unroll
        for (int nt = 0; nt < 8; nt++) {
            f32x4 c = {0.f, 0.f, 0.f, 0.f};
#pragma unroll
            for (int kk = 0; kk < 4; kk++) {
                short8 bf = *(const short8*)&w2t[(nt * 16 + lr) * 128 + kk * 32 + lk * 8];
                c = __builtin_amdgcn_mfma_f32_16x16x32_bf16(ha[kk], bf, c, 0, 0, 0);
            }
            o[nt] = c;
        }
        // epilogue: msg[pos[e]][col] = silu(o + b2) * h[src[e]][col]
        const int eb = wv * 16 + lk * 4;
        const float* hb0 = h + (size_t)s_src[eb + 0] * HD;
        const float* hb1 = h + (size_t)s_src[eb + 1] * HD;
        const float* hb2 = h + (size_t)s_src[eb + 2] * HD;
        const float* hb3 = h + (size_t)s_src[eb + 3] * HD;
        float* pb0 = msg + (size_t)s_pos[eb + 0] * HD;
        float* pb1 = msg + (size_t)s_pos[eb + 1] * HD;
        float* pb2 = msg + (size_t)s_pos[eb + 2] * HD;
        float* pb3 = msg + (size_t)s_pos[eb + 3] * HD;
#pragma unroll
        for (int nt = 0; nt < 8; nt++) {
            int col = nt * 16 + lr;
            pb0[col] = silu_f(o[nt][0] + b2v[nt]) * hb0[col];
            pb1[col] = silu_f(o[nt][1] + b2v[nt]) * hb1[col];
            pb2[col] = silu_f(o[nt][2] + b2v[nt]) * hb2[col];
            pb3[col] = silu_f(o[nt][3] + b2v[nt]) * hb3[col];
        }
        __syncthreads();
    }
}

// -------- node kernel: CSR-gather msg -> agg; MLP; residual+LN --------
__global__ __launch_bounds__(256, 2) void node_kernel_csr(
    const float* __restrict__ msg, const int* __restrict__ rowptr,
    const float* __restrict__ w1, const float* __restrict__ b1,
    const float* __restrict__ w2, const float* __restrict__ b2,
    const float* __restrict__ lg, const float* __restrict__ lb,
    float* __restrict__ h)
{
    __shared__ float s_in[64 * HD];
    __shared__ float s_hid[64 * HD];
    __shared__ int s_rp[65];
    const int t = threadIdx.x, cg = t & 31, rg = t >> 5, c4 = cg * 4;
    const int r0 = blockIdx.x * 64;

    if (t < 65) {
        int idx = r0 + t;
        if (idx > NATOM) idx = NATOM;
        s_rp[t] = rowptr[idx];
    }
    float4 bb1 = *(const float4*)&b1[c4];
    float4 bb2 = *(const float4*)&b2[c4];
    float4 g4 = *(const float4*)&lg[c4];
    float4 lb4 = *(const float4*)&lb[c4];
    __syncthreads();

#pragma unroll
    for (int i = 0; i < 8; i++) {
        int rr = rg * 8 + i;
        int beg = s_rp[rr], end = s_rp[rr + 1];
        float4 a0 = make_float4(0.f, 0.f, 0.f, 0.f);
        float4 a1 = make_float4(0.f, 0.f, 0.f, 0.f);
        int p = beg;
        for (; p + 1 < end; p += 2) {
            float4 m0 = *(const float4*)&msg[(size_t)p * HD + c4];
            float4 m1 = *(const float4*)&msg[(size_t)(p + 1) * HD + c4];
            a0.x += m0.x; a0.y += m0.y; a0.z += m0.z; a0.w += m0.w;
            a1.x += m1.x; a1.y += m1.y; a1.z += m1.z; a1.w += m1.w;
        }
        if (p < end) {
            float4 m0 = *(const float4*)&msg[(size_t)p * HD + c4];
            a0.x += m0.x; a0.y += m0.y; a0.z += m0.z; a0.w += m0.w;
        }
        a0.x += a1.x; a0.y += a1.y; a0.z += a1.z; a0.w += a1.w;
        *(float4*)&s_in[rr * HD + c4] = a0;
    }
    __syncthreads();

    float4 acc[8];
#pragma unroll
    for (int i = 0; i < 8; i++) acc[i] = bb1;
    for (int k = 0; k < HD; k++) {
        float4 w = *(const float4*)&w1[k * HD + c4];
#pragma unroll
        for (int i = 0; i < 8; i++) {
            float a = s_in[(rg * 8 + i) * HD + k];
            acc[i].x += a * w.x; acc[i].y += a * w.y; acc[i].z += a * w.z; acc[i].w += a * w.w;
        }
    }
#pragma unroll
    for (int i = 0; i < 8; i++) {
        float4 v = acc[i];
        v.x = silu_f(v.x); v.y = silu_f(v.y); v.z = silu_f(v.z); v.w = silu_f(v.w);
        *(float4*)&s_hid[(rg * 8 + i) * HD + c4] = v;
    }
    __syncthreads();

    float4 o[8];
#pragma unroll
    for (int i = 0; i < 8; i++) o[i] = bb2;
    for (int j = 0; j < HD; j++) {
        float4 w = *(const float4*)&w2[j * HD + c4];
#pragma unroll
        for (int i = 0; i < 8; i++) {
            float a = s_hid[(rg * 8 + i) * HD + j];
            o[i].x += a * w.x; o[i].y += a * w.y; o[i].z += a * w.z; o[i].w += a * w.w;
        }
    }
#pragma unroll
    for (int i = 0; i < 8; i++) {
        int r = r0 + rg * 8 + i;
        float4 hv = make_float4(0.f, 0.f, 0.f, 0.f);
        if (r < NATOM) hv = *(const float4*)&h[(size_t)r * HD + c4];
        float4 v;
        v.x = hv.x + o[i].x; v.y = hv.y + o[i].y; v.z = hv.z + o[i].z; v.w = hv.w + o[i].w;
        float s1 = v.x + v.y + v.z + v.w;
        float s2 = v.x * v.x + v.y * v.y + v.z * v.z + v.w * v.w;
#pragma unroll
        for (int off = 16; off >= 1; off >>= 1) {
            s1 += __shfl_xor(s1, off);
            s2 += __shfl_xor(s2, off);
        }
        float mean = s1 * (1.f / HD);
        float var = s2 * (1.f / HD) - mean * mean;
        float rstd = rsqrtf(var + LNEPS);
        float4 y;
        y.x = (v.x - mean) * rstd * g4.x + lb4.x;
        y.y = (v.y - mean) * rstd * g4.y + lb4.y;
        y.z = (v.z - mean) * rstd * g4.z + lb4.z;
        y.w = (v.w - mean) * rstd * g4.w + lb4.w;
        if (r < NATOM) *(float4*)&h[(size_t)r * HD + c4] = y;
    }
}

// ======== fallback path (small ws): round-1 proven atomic kernels ========
__global__ __launch_bounds__(256, 3) void edge_kernel_atomic(
    const float* __restrict__ edge_attr,
    const float* __restrict__ w1, const float* __restrict__ b1,
    const float* __restrict__ w2, const float* __restrict__ b2,
    const int* __restrict__ src, const int* __restrict__ dst,
    const float* __restrict__ h, float* __restrict__ agg)
{
    __shared__ float s_ea[64 * EFD];
    __shared__ float s_hid[64 * HD];
    __shared__ int s_src[64];
    __shared__ int s_dst[64];
    const int t = threadIdx.x, cg = t & 31, rg = t >> 5, c4 = cg * 4;

    float4 bb1 = *(const float4*)&b1[c4];
    float4 bb2 = *(const float4*)&b2[c4];

    const int ntiles = NEDGE / 64;
    for (int tile = blockIdx.x; tile < ntiles; tile += gridDim.x) {
        const int e0 = tile * 64;
        for (int i = t; i < 64 * EFD; i += 256) s_ea[i] = edge_attr[(size_t)e0 * EFD + i];
        if (t < 64) { s_src[t] = src[e0 + t]; s_dst[t] = dst[e0 + t]; }
        __syncthreads();
        float4 acc[8];
#pragma unroll
        for (int i = 0; i < 8; i++) acc[i] = bb1;
        for (int k = 0; k < EFD; k++) {
            float4 w = *(const float4*)&w1[k * HD + c4];
#pragma unroll
            for (int i = 0; i < 8; i++) {
                float a = s_ea[(rg * 8 + i) * EFD + k];
                acc[i].x += a * w.x; acc[i].y += a * w.y; acc[i].z += a * w.z; acc[i].w += a * w.w;
            }
        }
#pragma unroll
        for (int i = 0; i < 8; i++) {
            float4 v = acc[i];
            v.x = silu_f(v.x); v.y = silu_f(v.y); v.z = silu_f(v.z); v.w = silu_f(v.w);
            *(float4*)&s_hid[(rg * 8 + i) * HD + c4] = v;
        }
        __syncthreads();
        float4 o[8];
#pragma unroll
        for (int i = 0; i < 8; i++) o[i] = bb2;
        for (int j = 0; j < HD; j++) {
            float4 w = *(const float4*)&w2[j * HD + c4];
#pragma unroll
            for (int i = 0; i < 8; i++) {
                float a = s_hid[(rg * 8 + i) * HD + j];
                o[i].x += a * w.x; o[i].y += a * w.y; o[i].z += a * w.z; o[i].w += a * w.w;
            }
        }
#pragma unroll
        for (int i = 0; i < 8; i++) {
            int e = rg * 8 + i;
            int si = s_src[e], di = s_dst[e];
            float4 hs = *(const float4*)&h[(size_t)si * HD + c4];
            float* ap = agg + (size_t)di * HD + c4;
            atomicAdd(ap + 0, o[i].x * hs.x);
            atomicAdd(ap + 1, o[i].y * hs.y);
            atomicAdd(ap + 2, o[i].z * hs.z);
            atomicAdd(ap + 3, o[i].w * hs.w);
        }
        __syncthreads();
    }
}

__global__ __launch_bounds__(256, 2) void node_kernel_agg(
    const float* __restrict__ agg,
    const float* __restrict__ w1, const float* __restrict__ b1,
    const float* __restrict__ w2, const float* __restrict__ b2,
    const float* __restrict__ lg, const float* __restrict__ lb,
    float* __restrict__ h)
{
    __shared__ float s_in[64 * HD];
    __shared__ float s_hid[64 * HD];
    const int t = threadIdx.x, cg = t & 31, rg = t >> 5, c4 = cg * 4;
    const int r0 = blockIdx.x * 64;
    for (int i = t; i < 64 * HD; i += 256) {
        size_t g = (size_t)r0 * HD + i;
        s_in[i] = (g < (size_t)NATOM * HD) ? agg[g] : 0.f;
    }
    float4 bb1 = *(const float4*)&b1[c4];
    float4 bb2 = *(const float4*)&b2[c4];
    float4 g4 = *(const float4*)&lg[c4];
    float4 lb4 = *(const float4*)&lb[c4];
    __syncthreads();
    float4 acc[8];
#pragma unroll
    for (int i = 0; i < 8; i++) acc[i] = bb1;
    for (int k = 0; k < HD; k++) {
        float4 w = *(const float4*)&w1[k * HD + c4];
#pragma unroll
        for (int i = 0; i < 8; i++) {
            float a = s_in[(rg * 8 + i) * HD + k];
            acc[i].x += a * w.x; acc[i].y += a * w.y; acc[i].z += a * w.z; acc[i].w += a * w.w;
        }
    }
#pragma unroll
    for (int i = 0; i < 8; i++) {
        float4 v = acc[i];
        v.x = silu_f(v.x); v.y = silu_f(v.y); v.z = silu_f(v.z); v.w = silu_f(v.w);
        *(float4*)&s_hid[(rg * 8 + i) * HD + c4] = v;
    }
    __syncthreads();
    float4 o[8];
#pragma unroll
    for (int i = 0; i < 8; i++) o[i] = bb2;
    for (int j = 0; j < HD; j++) {
        float4 w = *(const float4*)&w2[j * HD + c4];
#pragma unroll
        for (int i = 0; i < 8; i++) {
            float a = s_hid[(rg * 8 + i) * HD + j];
            o[i].x += a * w.x; o[i].y += a * w.y; o[i].z += a * w.z; o[i].w += a * w.w;
        }
    }
#pragma unroll
    for (int i = 0; i < 8; i++) {
        int r = r0 + rg * 8 + i;
        float4 hv = make_float4(0.f, 0.f, 0.f, 0.f);
        if (r < NATOM) hv = *(const float4*)&h[(size_t)r * HD + c4];
        float4 v;
        v.x = hv.x + o[i].x; v.y = hv.y + o[i].y; v.z = hv.z + o[i].z; v.w = hv.w + o[i].w;
        float s1 = v.x + v.y + v.z + v.w;
        float s2 = v.x * v.x + v.y * v.y + v.z * v.z + v.w * v.w;
#pragma unroll
        for (int off = 16; off >= 1; off >>= 1) {
            s1 += __shfl_xor(s1, off);
            s2 += __shfl_xor(s2, off);
        }
        float mean = s1 * (1.f / HD);
        float var = s2 * (1.f / HD) - mean * mean;
        float rstd = rsqrtf(var + LNEPS);
        float4 y;
        y.x = (v.x - mean) * rstd * g4.x + lb4.x;
        y.y = (v.y - mean) * rstd * g4.y + lb4.y;
        y.z = (v.z - mean) * rstd * g4.z + lb4.z;
        y.w = (v.w - mean) * rstd * g4.w + lb4.w;
        if (r < NATOM) *(float4*)&h[(size_t)r * HD + c4] = y;
    }
}

// -------- pool + head: one block per graph ----------
__global__ __launch_bounds__(128) void head_kernel(
    const float* __restrict__ h, const float* __restrict__ gfeat,
    const float* __restrict__ gw, const float* __restrict__ gb,
    const float* __restrict__ ow1, const float* __restrict__ ob1,
    const float* __restrict__ ow2, const float* __restrict__ ob2,
    const float* __restrict__ ow3, const float* __restrict__ ob3,
    const int* __restrict__ batch, float* __restrict__ out)
{
    __shared__ float comb[2 * HD];
    __shared__ float h1[HD];
    __shared__ float h2[64];
    const int b = blockIdx.x;
    const int c = threadIdx.x;

    int lo = 0, hi = NATOM;
    while (lo < hi) { int m = (lo + hi) >> 1; if (batch[m] < b) lo = m + 1; else hi = m; }
    const int start = lo;
    hi = NATOM;
    while (lo < hi) { int m = (lo + hi) >> 1; if (batch[m] < b + 1) lo = m + 1; else hi = m; }
    const int end = lo;

    float s = 0.f;
    for (int r = start; r < end; r++) s += h[(size_t)r * HD + c];
    float cnt = (float)(end - start);
    if (cnt < 1.f) cnt = 1.f;
    comb[c] = s / cnt;

    float a = gb[c];
    for (int k = 0; k < GFD; k++) a += gfeat[b * GFD + k] * gw[k * HD + c];
    comb[HD + c] = silu_f(a);
    __syncthreads();

    float u = ob1[c];
    for (int j = 0; j < 2 * HD; j++) u += comb[j] * ow1[j * HD + c];
    h1[c] = silu_f(u);
    __syncthreads();

    if (c < 64) {
        float v = ob2[c];
        for (int j = 0; j < HD; j++) v += h1[j] * ow2[j * 64 + c];
        h2[c] = silu_f(v);
    }
    __syncthreads();

    if (c < TOUT) {
        float v = ob3[c];
        for (int j = 0; j < 64; j++) v += h2[j] * ow3[j * TOUT + c];
        out[b * TOUT + c] = v;
    }
}

extern "C" void kernel_launch(void* const* d_in, const int* in_sizes, int n_in,
                              void* d_out, int out_size, void* d_ws, size_t ws_size,
                              hipStream_t stream) {
    const float* x        = (const float*)d_in[0];
    const float* edge_attr= (const float*)d_in[1];
    const float* gfeat    = (const float*)d_in[2];
    const float* ae_w1    = (const float*)d_in[3];
    const float* ae_b1    = (const float*)d_in[4];
    const float* ae_w2    = (const float*)d_in[5];
    const float* ae_b2    = (const float*)d_in[6];
    const float* ew1      = (const float*)d_in[7];
    const float* eb1      = (const float*)d_in[8];
    const float* ew2      = (const float*)d_in[9];
    const float* eb2      = (const float*)d_in[10];
    const float* nw1      = (const float*)d_in[11];
    const float* nb1      = (const float*)d_in[12];
    const float* nw2      = (const float*)d_in[13];
    const float* nb2      = (const float*)d_in[14];
    const float* ln_g     = (const float*)d_in[15];
    const float* ln_b     = (const float*)d_in[16];
    const float* gw       = (const float*)d_in[17];
    const float* gb       = (const float*)d_in[18];
    const float* ow1      = (const float*)d_in[19];
    const float* ob1      = (const float*)d_in[20];
    const float* ow2      = (const float*)d_in[21];
    const float* ob2      = (const float*)d_in[22];
    const float* ow3      = (const float*)d_in[23];
    const float* ob3      = (const float*)d_in[24];
    const int* edge_index = (const int*)d_in[25];
    const int* batch      = (const int*)d_in[26];

    const int* src = edge_index;
    const int* dst = edge_index + NEDGE;
    const int row_blocks = (NATOM + 63) / 64;  // 782

    // workspace layout (all block sizes multiples of 4 ints -> 16B alignment preserved)
    float* h    = (float*)d_ws;                           // NATOM*HD f32
    float* msg  = h + (size_t)NATOM * HD;                 // NEDGE*HD f32
    int* count  = (int*)(msg + (size_t)NEDGE * HD);       // NATOM
    int* rowptr = count + NATOM;                          // NATOM+4 (padded)
    int* cursor = rowptr + NATOM + 4;                     // NATOM
    int* pos    = cursor + NATOM;                         // NEDGE
    unsigned short* w1t = (unsigned short*)(pos + NEDGE); // NL*HD*64 bf16
    unsigned short* w2t = w1t + NL * HD * 64;             // NL*HD*HD bf16
    size_t need = (size_t)((char*)(w2t + NL * HD * HD) - (char*)d_ws);

    if (ws_size >= need) {
        // ---- sort prologue + weight conversion ----
        hipMemsetAsync(count, 0, NATOM * sizeof(int), stream);
        hist_kernel<<<1024, 256, 0, stream>>>(dst, count);
        scan_kernel<<<1, 256, 0, stream>>>(count, rowptr, cursor);
        pos_kernel<<<1024, 256, 0, stream>>>(dst, cursor, pos);
        wconv_kernel<<<(NL * HD * 64 + NL * HD * HD + 255) / 256, 256, 0, stream>>>(ew1, ew2, w1t, w2t);

        atom_kernel<<<row_blocks, 256, 0, stream>>>(x, ae_w1, ae_b1, ae_w2, ae_b2, h);

        for (int l = 0; l < NL; l++) {
            edge_kernel_mfma<<<2048, 256, 0, stream>>>(
                edge_attr,
                w1t + (size_t)l * HD * 64, eb1 + (size_t)l * HD,
                w2t + (size_t)l * HD * HD, eb2 + (size_t)l * HD,
                src, pos, h, msg);
            node_kernel_csr<<<row_blocks, 256, 0, stream>>>(
                msg, rowptr,
                nw1 + (size_t)l * HD * HD, nb1 + (size_t)l * HD,
                nw2 + (size_t)l * HD * HD, nb2 + (size_t)l * HD,
                ln_g + (size_t)l * HD, ln_b + (size_t)l * HD,
                h);
        }
    } else {
        // ---- fallback: atomic aggregation ----
        float* agg = h + (size_t)NATOM * HD;
        atom_kernel<<<row_blocks, 256, 0, stream>>>(x, ae_w1, ae_b1, ae_w2, ae_b2, h);
        for (int l = 0; l < NL; l++) {
            hipMemsetAsync(agg, 0, (size_t)NATOM * HD * sizeof(float), stream);
            edge_kernel_atomic<<<2048, 256, 0, stream>>>(
                edge_attr,
                ew1 + (size_t)l * EFD * HD, eb1 + (size_t)l * HD,
                ew2 + (size_t)l * HD * HD,  eb2 + (size_t)l * HD,
                src, dst, h, agg);
            node_kernel_agg<<<row_blocks, 256, 0, stream>>>(
                agg,
                nw1 + (size_t)l * HD * HD, nb1 + (size_t)l * HD,
                nw2 + (size_t)l * HD * HD, nb2 + (size_t)l * HD,
                ln_g + (size_t)l * HD, ln_b + (size_t)l * HD,
                h);
        }
    }

    head_kernel<<<NGRAPH, 128, 0, stream>>>(
        h, gfeat, gw, gb, ow1, ob1, ow2, ob2, ow3, ob3, batch, (float*)d_out);
}

// Round 6
// 2637.970 us; speedup vs baseline: 1.6494x; 1.6494x over previous
//
#include <hip/hip_runtime.h>
#include <math.h>

#define NATOM 50000
#define NEDGE 800000
#define NGRAPH 256
#define HD 128
#define NL 4
#define AFD 108
#define EFD 41
#define GFD 239
#define TOUT 5
#define LNEPS 1e-5f

typedef __attribute__((ext_vector_type(8))) short short8;
typedef __attribute__((ext_vector_type(4))) float f32x4;

__device__ __forceinline__ float silu_f(float v) { return v / (1.f + __expf(-v)); }

__device__ __forceinline__ unsigned short f2b(float f) {
    union { float f; unsigned u; } x; x.f = f;
    unsigned r = x.u + 0x7fffu + ((x.u >> 16) & 1u);   // RNE
    return (unsigned short)(r >> 16);
}

// ---------------- CSR build ----------------
__global__ void hist_kernel(const int* __restrict__ dst, int* __restrict__ count) {
    for (int e = blockIdx.x * blockDim.x + threadIdx.x; e < NEDGE; e += gridDim.x * blockDim.x)
        atomicAdd(&count[dst[e]], 1);
}

__global__ void scan_kernel(const int* __restrict__ count, int* __restrict__ rowptr,
                            int* __restrict__ cursor) {
    __shared__ int s_w[4];
    __shared__ int s_carry;
    const int t = threadIdx.x, lane = t & 63, wv = t >> 6;
    if (t == 0) { s_carry = 0; rowptr[0] = 0; }
    __syncthreads();
    for (int base = 0; base < NATOM; base += 256) {
        int v = (base + t < NATOM) ? count[base + t] : 0;
        int x = v;
#pragma unroll
        for (int off = 1; off < 64; off <<= 1) {
            int y = __shfl_up(x, off);
            if (lane >= off) x += y;
        }
        if (lane == 63) s_w[wv] = x;
        __syncthreads();
        int wvoff = s_carry;
        for (int w = 0; w < wv; w++) wvoff += s_w[w];
        int incl = x + wvoff;
        if (base + t < NATOM) { rowptr[base + t + 1] = incl; cursor[base + t] = incl - v; }
        __syncthreads();
        if (t == 255) s_carry = incl;
        __syncthreads();
    }
}

// pos[e] = dst-sorted position; ssrc[pos[e]] = src[e] (if ssrc != null)
__global__ void pos_kernel(const int* __restrict__ dst, const int* __restrict__ src,
                           int* __restrict__ cursor, int* __restrict__ pos,
                           int* __restrict__ ssrc) {
    for (int e = blockIdx.x * blockDim.x + threadIdx.x; e < NEDGE; e += gridDim.x * blockDim.x) {
        int d = dst[e];
        int p = atomicAdd(&cursor[d], 1);
        pos[e] = p;
        if (ssrc) ssrc[p] = src[e];
    }
}

// ---- weight conversion: w1t[l][n][k<64] = bf16(ew1[l][k][n]) (k>=41 -> 0); w2t[l][n][k] ----
__global__ void wconv_kernel(const float* __restrict__ ew1, const float* __restrict__ ew2,
                             unsigned short* __restrict__ w1t, unsigned short* __restrict__ w2t) {
    int idx = blockIdx.x * 256 + threadIdx.x;
    const int n1 = NL * HD * 64;
    if (idx < n1) {
        int l = idx / (HD * 64); int rem = idx - l * HD * 64; int n = rem >> 6; int k = rem & 63;
        float v = (k < EFD) ? ew1[((size_t)l * EFD + k) * HD + n] : 0.f;
        w1t[idx] = f2b(v);
    } else {
        int j = idx - n1;
        if (j < NL * HD * HD) {
            int l = j / (HD * HD); int rem = j - l * HD * HD; int n = rem >> 7; int k = rem & 127;
            w2t[j] = f2b(ew2[((size_t)l * HD + k) * HD + n]);
        }
    }
}

// ---------------- atom embedding ----------------
__global__ __launch_bounds__(256, 2) void atom_kernel(
    const float* __restrict__ x, const float* __restrict__ w1, const float* __restrict__ b1,
    const float* __restrict__ w2, const float* __restrict__ b2, float* __restrict__ h)
{
    __shared__ float s_x[64 * AFD];
    __shared__ float s_hid[64 * HD];
    const int t = threadIdx.x, cg = t & 31, rg = t >> 5, c4 = cg * 4;
    const int r0 = blockIdx.x * 64;

    for (int i = t; i < 64 * AFD; i += 256) {
        size_t g = (size_t)r0 * AFD + i;
        s_x[i] = (g < (size_t)NATOM * AFD) ? x[g] : 0.f;
    }
    float4 bb1 = *(const float4*)&b1[c4];
    float4 bb2 = *(const float4*)&b2[c4];
    __syncthreads();

    float4 acc[8];
#pragma unroll
    for (int i = 0; i < 8; i++) acc[i] = bb1;
    for (int k = 0; k < AFD; k++) {
        float4 w = *(const float4*)&w1[k * HD + c4];
#pragma unroll
        for (int i = 0; i < 8; i++) {
            float a = s_x[(rg * 8 + i) * AFD + k];
            acc[i].x += a * w.x; acc[i].y += a * w.y; acc[i].z += a * w.z; acc[i].w += a * w.w;
        }
    }
#pragma unroll
    for (int i = 0; i < 8; i++) {
        float4 v = acc[i];
        v.x = silu_f(v.x); v.y = silu_f(v.y); v.z = silu_f(v.z); v.w = silu_f(v.w);
        *(float4*)&s_hid[(rg * 8 + i) * HD + c4] = v;
    }
    __syncthreads();

    float4 o[8];
#pragma unroll
    for (int i = 0; i < 8; i++) o[i] = bb2;
    for (int j = 0; j < HD; j++) {
        float4 w = *(const float4*)&w2[j * HD + c4];
#pragma unroll
        for (int i = 0; i < 8; i++) {
            float a = s_hid[(rg * 8 + i) * HD + j];
            o[i].x += a * w.x; o[i].y += a * w.y; o[i].z += a * w.z; o[i].w += a * w.w;
        }
    }
#pragma unroll
    for (int i = 0; i < 8; i++) {
        int r = r0 + rg * 8 + i;
        if (r < NATOM) *(float4*)&h[(size_t)r * HD + c4] = o[i];
    }
}

// -------- wf_kernel: pure streaming edge MLP via MFMA, weights in registers --------
// Each wave owns 32 output cols (nt in {2*wv, 2*wv+1}) for all 64 edges of the tile.
// A-frag: lane l holds A[l&15][(l>>4)*8+j]; B-frag: B[(l>>4)*8+j][l&15];
// D reg r -> D[(l>>4)*4+r][l&15]  (m89-verified layouts)
__global__ __launch_bounds__(256, 2) void wf_kernel(
    const float* __restrict__ edge_attr,
    const unsigned short* __restrict__ w1t, const float* __restrict__ b1,
    const unsigned short* __restrict__ w2t, const float* __restrict__ b2,
    const int* __restrict__ pos, float* __restrict__ wf)
{
    __shared__ __align__(16) unsigned short s_a1[64 * 64];    // 8 KB, swizzled bf16 (K-padded)
    __shared__ __align__(16) unsigned short s_hid[64 * 128];  // 16 KB, swizzled bf16
    __shared__ __align__(16) float s_out[64 * 132];           // 33.8 KB, +4 pad vs bank conflicts
    __shared__ int s_pos[64];

    const int t = threadIdx.x;
    const int wv = t >> 6, lane = t & 63;
    const int lr = lane & 15, lk = lane >> 4;

    // persistent B-fragments (48 VGPRs) + biases, loaded once
    short8 wb1[2][2], wb2[2][4];
    float b1v[2], b2v[2];
#pragma unroll
    for (int nt = 0; nt < 2; nt++) {
        int n = (wv * 2 + nt) * 16 + lr;
        b1v[nt] = b1[n]; b2v[nt] = b2[n];
#pragma unroll
        for (int kk = 0; kk < 2; kk++) wb1[nt][kk] = *(const short8*)&w1t[n * 64 + kk * 32 + lk * 8];
#pragma unroll
        for (int kk = 0; kk < 4; kk++) wb2[nt][kk] = *(const short8*)&w2t[n * 128 + kk * 32 + lk * 8];
    }
    // zero-init s_a1: K-pad 41..63 stays zero forever
    for (int i = t; i < 64 * 64; i += 256) s_a1[i] = 0;
    __syncthreads();

    const int ntiles = NEDGE / 64;
    for (int tile = blockIdx.x; tile < ntiles; tile += gridDim.x) {
        const int e0 = tile * 64;
        if (t < 64) s_pos[t] = pos[e0 + t];
        for (int i = t; i < 64 * EFD; i += 256) {
            int e = i / EFD, k = i - e * EFD;
            int byte = e * 128 + ((2 * k) ^ ((e & 7) << 4));
            *(unsigned short*)((char*)s_a1 + byte) = f2b(edge_attr[(size_t)e0 * EFD + i]);
        }
        __syncthreads();

        // ---- GEMM1: hid[64,128] = silu(ea[64,64] @ w1) ---- (this wave: its 32 cols)
        f32x4 acc1[4][2];
#pragma unroll
        for (int rt = 0; rt < 4; rt++) {
            int row = rt * 16 + lr;
            int sw = (row & 7) << 4;
            short8 a0 = *(const short8*)((const char*)s_a1 + row * 128 + ((lk * 16) ^ sw));
            short8 a1 = *(const short8*)((const char*)s_a1 + row * 128 + ((64 + lk * 16) ^ sw));
#pragma unroll
            for (int nt = 0; nt < 2; nt++) {
                f32x4 c = {0.f, 0.f, 0.f, 0.f};
                c = __builtin_amdgcn_mfma_f32_16x16x32_bf16(a0, wb1[nt][0], c, 0, 0, 0);
                c = __builtin_amdgcn_mfma_f32_16x16x32_bf16(a1, wb1[nt][1], c, 0, 0, 0);
                acc1[rt][nt] = c;
            }
        }
        // bias + silu -> bf16 -> s_hid (swizzled)
#pragma unroll
        for (int rt = 0; rt < 4; rt++) {
#pragma unroll
            for (int nt = 0; nt < 2; nt++) {
#pragma unroll
                for (int r = 0; r < 4; r++) {
                    int row = rt * 16 + lk * 4 + r;
                    int col = (wv * 2 + nt) * 16 + lr;
                    float v = silu_f(acc1[rt][nt][r] + b1v[nt]);
                    int byte = row * 256 + ((2 * col) ^ ((row & 7) << 4));
                    *(unsigned short*)((char*)s_hid + byte) = f2b(v);
                }
            }
        }
        __syncthreads();

        // ---- GEMM2: o[64,128] = hid[64,128] @ w2 ---- (this wave: its 32 cols)
        f32x4 acc2[4][2];
#pragma unroll
        for (int rt = 0; rt < 4; rt++) {
            int row = rt * 16 + lr;
            int sw = (row & 7) << 4;
            short8 ha[4];
#pragma unroll
            for (int kk = 0; kk < 4; kk++)
                ha[kk] = *(const short8*)((const char*)s_hid + row * 256 + ((kk * 64 + lk * 16) ^ sw));
#pragma unroll
            for (int nt = 0; nt < 2; nt++) {
                f32x4 c = {0.f, 0.f, 0.f, 0.f};
#pragma unroll
                for (int kk = 0; kk < 4; kk++)
                    c = __builtin_amdgcn_mfma_f32_16x16x32_bf16(ha[kk], wb2[nt][kk], c, 0, 0, 0);
                acc2[rt][nt] = c;
            }
        }
        // bias + silu -> fp32 s_out (padded: 2-way max bank aliasing = free)
#pragma unroll
        for (int rt = 0; rt < 4; rt++)
#pragma unroll
            for (int nt = 0; nt < 2; nt++)
#pragma unroll
                for (int r = 0; r < 4; r++)
                    s_out[(rt * 16 + lk * 4 + r) * 132 + (wv * 2 + nt) * 16 + lr] =
                        silu_f(acc2[rt][nt][r] + b2v[nt]);
        __syncthreads();

        // coalesced scatter: Wf row -> dst-sorted position
        const int tc = t & 31, tr = t >> 5;
#pragma unroll
        for (int i = 0; i < 8; i++) {
            int row = tr * 8 + i;
            int p = s_pos[row];
            *(float4*)&wf[(size_t)p * HD + tc * 4] = *(const float4*)&s_out[row * 132 + tc * 4];
        }
        __syncthreads();
    }
}

// -------- mode-B helper: wf[pos[e]] *= h[src[e]] (in-place, rows touched once) --------
__global__ void mul_kernel(const float* __restrict__ h, const int* __restrict__ src,
                           const int* __restrict__ pos, float* __restrict__ wf) {
    for (long long idx = (long long)blockIdx.x * 256 + threadIdx.x;
         idx < (long long)NEDGE * 32; idx += (long long)gridDim.x * 256) {
        int e = (int)(idx >> 5), q = (int)(idx & 31);
        int p = pos[e], s = src[e];
        float4 w = *(const float4*)&wf[(size_t)p * HD + q * 4];
        float4 hv = *(const float4*)&h[(size_t)s * HD + q * 4];
        w.x *= hv.x; w.y *= hv.y; w.z *= hv.z; w.w *= hv.w;
        *(float4*)&wf[(size_t)p * HD + q * 4] = w;
    }
}

// -------- node kernel: CSR-sum (optionally fused h-gather multiply), MLP, residual+LN --------
template<bool GATHER>
__global__ __launch_bounds__(256, 2) void node_kernel(
    const float* __restrict__ wfm, const int* __restrict__ rowptr, const int* __restrict__ ssrc,
    const float* __restrict__ h_in,
    const float* __restrict__ w1, const float* __restrict__ b1,
    const float* __restrict__ w2, const float* __restrict__ b2,
    const float* __restrict__ lg, const float* __restrict__ lb,
    float* __restrict__ h_out)
{
    __shared__ float s_in[64 * HD];
    __shared__ float s_hid[64 * HD];
    __shared__ int s_rp[65];
    const int t = threadIdx.x, cg = t & 31, rg = t >> 5, c4 = cg * 4;
    const int r0 = blockIdx.x * 64;

    if (t < 65) {
        int idx = r0 + t;
        if (idx > NATOM) idx = NATOM;
        s_rp[t] = rowptr[idx];
    }
    float4 bb1 = *(const float4*)&b1[c4];
    float4 bb2 = *(const float4*)&b2[c4];
    float4 g4 = *(const float4*)&lg[c4];
    float4 lb4 = *(const float4*)&lb[c4];
    __syncthreads();

#pragma unroll
    for (int i = 0; i < 8; i++) {
        int rr = rg * 8 + i;
        int beg = s_rp[rr], end = s_rp[rr + 1];
        float4 a0 = make_float4(0.f, 0.f, 0.f, 0.f);
        float4 a1 = make_float4(0.f, 0.f, 0.f, 0.f);
        int p = beg;
        for (; p + 1 < end; p += 2) {
            float4 m0 = *(const float4*)&wfm[(size_t)p * HD + c4];
            float4 m1 = *(const float4*)&wfm[(size_t)(p + 1) * HD + c4];
            if (GATHER) {
                int s0 = ssrc[p], s1 = ssrc[p + 1];
                float4 h0 = *(const float4*)&h_in[(size_t)s0 * HD + c4];
                float4 h1 = *(const float4*)&h_in[(size_t)s1 * HD + c4];
                a0.x = fmaf(m0.x, h0.x, a0.x); a0.y = fmaf(m0.y, h0.y, a0.y);
                a0.z = fmaf(m0.z, h0.z, a0.z); a0.w = fmaf(m0.w, h0.w, a0.w);
                a1.x = fmaf(m1.x, h1.x, a1.x); a1.y = fmaf(m1.y, h1.y, a1.y);
                a1.z = fmaf(m1.z, h1.z, a1.z); a1.w = fmaf(m1.w, h1.w, a1.w);
            } else {
                a0.x += m0.x; a0.y += m0.y; a0.z += m0.z; a0.w += m0.w;
                a1.x += m1.x; a1.y += m1.y; a1.z += m1.z; a1.w += m1.w;
            }
        }
        if (p < end) {
            float4 m0 = *(const float4*)&wfm[(size_t)p * HD + c4];
            if (GATHER) {
                int s0 = ssrc[p];
                float4 h0 = *(const float4*)&h_in[(size_t)s0 * HD + c4];
                a0.x = fmaf(m0.x, h0.x, a0.x); a0.y = fmaf(m0.y, h0.y, a0.y);
                a0.z = fmaf(m0.z, h0.z, a0.z); a0.w = fmaf(m0.w, h0.w, a0.w);
            } else {
                a0.x += m0.x; a0.y += m0.y; a0.z += m0.z; a0.w += m0.w;
            }
        }
        a0.x += a1.x; a0.y += a1.y; a0.z += a1.z; a0.w += a1.w;
        *(float4*)&s_in[rr * HD + c4] = a0;
    }
    __syncthreads();

    float4 acc[8];
#pragma unroll
    for (int i = 0; i < 8; i++) acc[i] = bb1;
    for (int k = 0; k < HD; k++) {
        float4 w = *(const float4*)&w1[k * HD + c4];
#pragma unroll
        for (int i = 0; i < 8; i++) {
            float a = s_in[(rg * 8 + i) * HD + k];
            acc[i].x += a * w.x; acc[i].y += a * w.y; acc[i].z += a * w.z; acc[i].w += a * w.w;
        }
    }
#pragma unroll
    for (int i = 0; i < 8; i++) {
        float4 v = acc[i];
        v.x = silu_f(v.x); v.y = silu_f(v.y); v.z = silu_f(v.z); v.w = silu_f(v.w);
        *(float4*)&s_hid[(rg * 8 + i) * HD + c4] = v;
    }
    __syncthreads();

    float4 o[8];
#pragma unroll
    for (int i = 0; i < 8; i++) o[i] = bb2;
    for (int j = 0; j < HD; j++) {
        float4 w = *(const float4*)&w2[j * HD + c4];
#pragma unroll
        for (int i = 0; i < 8; i++) {
            float a = s_hid[(rg * 8 + i) * HD + j];
            o[i].x += a * w.x; o[i].y += a * w.y; o[i].z += a * w.z; o[i].w += a * w.w;
        }
    }
#pragma unroll
    for (int i = 0; i < 8; i++) {
        int r = r0 + rg * 8 + i;
        float4 hv = make_float4(0.f, 0.f, 0.f, 0.f);
        if (r < NATOM) hv = *(const float4*)&h_in[(size_t)r * HD + c4];
        float4 v;
        v.x = hv.x + o[i].x; v.y = hv.y + o[i].y; v.z = hv.z + o[i].z; v.w = hv.w + o[i].w;
        float s1 = v.x + v.y + v.z + v.w;
        float s2 = v.x * v.x + v.y * v.y + v.z * v.z + v.w * v.w;
#pragma unroll
        for (int off = 16; off >= 1; off >>= 1) {
            s1 += __shfl_xor(s1, off);
            s2 += __shfl_xor(s2, off);
        }
        float mean = s1 * (1.f / HD);
        float var = s2 * (1.f / HD) - mean * mean;
        float rstd = rsqrtf(var + LNEPS);
        float4 y;
        y.x = (v.x - mean) * rstd * g4.x + lb4.x;
        y.y = (v.y - mean) * rstd * g4.y + lb4.y;
        y.z = (v.z - mean) * rstd * g4.z + lb4.z;
        y.w = (v.w - mean) * rstd * g4.w + lb4.w;
        if (r < NATOM) *(float4*)&h_out[(size_t)r * HD + c4] = y;
    }
}

// -------- pool + head ----------
__global__ __launch_bounds__(128) void head_kernel(
    const float* __restrict__ h, const float* __restrict__ gfeat,
    const float* __restrict__ gw, const float* __restrict__ gb,
    const float* __restrict__ ow1, const float* __restrict__ ob1,
    const float* __restrict__ ow2, const float* __restrict__ ob2,
    const float* __restrict__ ow3, const float* __restrict__ ob3,
    const int* __restrict__ batch, float* __restrict__ out)
{
    __shared__ float comb[2 * HD];
    __shared__ float h1[HD];
    __shared__ float h2[64];
    const int b = blockIdx.x;
    const int c = threadIdx.x;

    int lo = 0, hi = NATOM;
    while (lo < hi) { int m = (lo + hi) >> 1; if (batch[m] < b) lo = m + 1; else hi = m; }
    const int start = lo;
    hi = NATOM;
    while (lo < hi) { int m = (lo + hi) >> 1; if (batch[m] < b + 1) lo = m + 1; else hi = m; }
    const int end = lo;

    float s = 0.f;
    for (int r = start; r < end; r++) s += h[(size_t)r * HD + c];
    float cnt = (float)(end - start);
    if (cnt < 1.f) cnt = 1.f;
    comb[c] = s / cnt;

    float a = gb[c];
    for (int k = 0; k < GFD; k++) a += gfeat[b * GFD + k] * gw[k * HD + c];
    comb[HD + c] = silu_f(a);
    __syncthreads();

    float u = ob1[c];
    for (int j = 0; j < 2 * HD; j++) u += comb[j] * ow1[j * HD + c];
    h1[c] = silu_f(u);
    __syncthreads();

    if (c < 64) {
        float v = ob2[c];
        for (int j = 0; j < HD; j++) v += h1[j] * ow2[j * 64 + c];
        h2[c] = silu_f(v);
    }
    __syncthreads();

    if (c < TOUT) {
        float v = ob3[c];
        for (int j = 0; j < 64; j++) v += h2[j] * ow3[j * TOUT + c];
        out[b * TOUT + c] = v;
    }
}

extern "C" void kernel_launch(void* const* d_in, const int* in_sizes, int n_in,
                              void* d_out, int out_size, void* d_ws, size_t ws_size,
                              hipStream_t stream) {
    const float* x        = (const float*)d_in[0];
    const float* edge_attr= (const float*)d_in[1];
    const float* gfeat    = (const float*)d_in[2];
    const float* ae_w1    = (const float*)d_in[3];
    const float* ae_b1    = (const float*)d_in[4];
    const float* ae_w2    = (const float*)d_in[5];
    const float* ae_b2    = (const float*)d_in[6];
    const float* ew1      = (const float*)d_in[7];
    const float* eb1      = (const float*)d_in[8];
    const float* ew2      = (const float*)d_in[9];
    const float* eb2      = (const float*)d_in[10];
    const float* nw1      = (const float*)d_in[11];
    const float* nb1      = (const float*)d_in[12];
    const float* nw2      = (const float*)d_in[13];
    const float* nb2      = (const float*)d_in[14];
    const float* ln_g     = (const float*)d_in[15];
    const float* ln_b     = (const float*)d_in[16];
    const float* gw       = (const float*)d_in[17];
    const float* gb       = (const float*)d_in[18];
    const float* ow1      = (const float*)d_in[19];
    const float* ob1      = (const float*)d_in[20];
    const float* ow2      = (const float*)d_in[21];
    const float* ob2      = (const float*)d_in[22];
    const float* ow3      = (const float*)d_in[23];
    const float* ob3      = (const float*)d_in[24];
    const int* edge_index = (const int*)d_in[25];
    const int* batch      = (const int*)d_in[26];

    const int* src = edge_index;
    const int* dst = edge_index + NEDGE;
    const int row_blocks = (NATOM + 63) / 64;  // 782

    // workspace: h0 | [h1] | wf | count | rowptr | cursor | pos | [ssrc] | w1t | w2t
    // mode A (fused gather in node, h ping-pong): needs +h1 +ssrc over proven round-4 footprint.
    // mode B (in-place mul kernel): exactly the round-4-proven footprint.
    float* h0 = (float*)d_ws;
    size_t fA = (size_t)NATOM * HD * 2 + (size_t)NEDGE * HD;
    size_t intsA = (size_t)NATOM * 3 + 4 + (size_t)NEDGE * 2;
    size_t wele = (size_t)NL * HD * 64 + (size_t)NL * HD * HD;
    size_t needA = fA * 4 + intsA * 4 + wele * 2;

    bool modeA = (ws_size >= needA);

    float* h1   = modeA ? (h0 + (size_t)NATOM * HD) : h0;
    float* wf   = (modeA ? h1 : h0) + (size_t)NATOM * HD;
    int* count  = (int*)(wf + (size_t)NEDGE * HD);
    int* rowptr = count + NATOM;
    int* cursor = rowptr + NATOM + 4;
    int* pos    = cursor + NATOM;
    int* ssrc   = modeA ? (pos + NEDGE) : nullptr;
    unsigned short* w1t = (unsigned short*)(modeA ? (ssrc + NEDGE) : (pos + NEDGE));
    unsigned short* w2t = w1t + NL * HD * 64;

    // ---- prologue: counting sort + weight conversion ----
    hipMemsetAsync(count, 0, NATOM * sizeof(int), stream);
    hist_kernel<<<1024, 256, 0, stream>>>(dst, count);
    scan_kernel<<<1, 256, 0, stream>>>(count, rowptr, cursor);
    pos_kernel<<<1024, 256, 0, stream>>>(dst, src, cursor, pos, ssrc);
    wconv_kernel<<<(NL * HD * 64 + NL * HD * HD + 255) / 256, 256, 0, stream>>>(ew1, ew2, w1t, w2t);

    atom_kernel<<<row_blocks, 256, 0, stream>>>(x, ae_w1, ae_b1, ae_w2, ae_b2, h0);

    const float* cur = h0;
    float* nxt = modeA ? h1 : h0;
    for (int l = 0; l < NL; l++) {
        wf_kernel<<<2048, 256, 0, stream>>>(
            edge_attr,
            w1t + (size_t)l * HD * 64, eb1 + (size_t)l * HD,
            w2t + (size_t)l * HD * HD, eb2 + (size_t)l * HD,
            pos, wf);
        if (modeA) {
            node_kernel<true><<<row_blocks, 256, 0, stream>>>(
                wf, rowptr, ssrc, cur,
                nw1 + (size_t)l * HD * HD, nb1 + (size_t)l * HD,
                nw2 + (size_t)l * HD * HD, nb2 + (size_t)l * HD,
                ln_g + (size_t)l * HD, ln_b + (size_t)l * HD,
                nxt);
            const float* tmp = cur; cur = nxt; nxt = (float*)tmp;
        } else {
            mul_kernel<<<2048, 256, 0, stream>>>(h0, src, pos, wf);
            node_kernel<false><<<row_blocks, 256, 0, stream>>>(
                wf, rowptr, nullptr, h0,
                nw1 + (size_t)l * HD * HD, nb1 + (size_t)l * HD,
                nw2 + (size_t)l * HD * HD, nb2 + (size_t)l * HD,
                ln_g + (size_t)l * HD, ln_b + (size_t)l * HD,
                h0);
        }
    }

    head_kernel<<<NGRAPH, 128, 0, stream>>>(
        cur, gfeat, gw, gb, ow1, ob1, ow2, ob2, ow3, ob3, batch, (float*)d_out);
}

// Round 8
// 2208.024 us; speedup vs baseline: 1.9706x; 1.1947x over previous
//
#include <hip/hip_runtime.h>
#include <math.h>

#define NATOM 50000
#define NEDGE 800000
#define NGRAPH 256
#define HD 128
#define NL 4
#define AFD 108
#define EFD 41
#define GFD 239
#define TOUT 5
#define LNEPS 1e-5f

typedef __attribute__((ext_vector_type(8))) short short8;
typedef __attribute__((ext_vector_type(4))) float f32x4;

// fast silu: v_exp + v_rcp (1-ulp) instead of IEEE divide sequence
__device__ __forceinline__ float silu_f(float v) {
    return v * __builtin_amdgcn_rcpf(1.f + __expf(-v));
}

__device__ __forceinline__ unsigned short f2b(float f) {
    union { float f; unsigned u; } x; x.f = f;
    unsigned r = x.u + 0x7fffu + ((x.u >> 16) & 1u);   // RNE
    return (unsigned short)(r >> 16);
}

// ---------------- CSR build ----------------
__global__ void hist_kernel(const int* __restrict__ dst, int* __restrict__ count) {
    for (int e = blockIdx.x * blockDim.x + threadIdx.x; e < NEDGE; e += gridDim.x * blockDim.x)
        atomicAdd(&count[dst[e]], 1);
}

__global__ void scan_kernel(const int* __restrict__ count, int* __restrict__ rowptr,
                            int* __restrict__ cursor) {
    __shared__ int s_w[4];
    __shared__ int s_carry;
    const int t = threadIdx.x, lane = t & 63, wv = t >> 6;
    if (t == 0) { s_carry = 0; rowptr[0] = 0; }
    __syncthreads();
    for (int base = 0; base < NATOM; base += 256) {
        int v = (base + t < NATOM) ? count[base + t] : 0;
        int x = v;
#pragma unroll
        for (int off = 1; off < 64; off <<= 1) {
            int y = __shfl_up(x, off);
            if (lane >= off) x += y;
        }
        if (lane == 63) s_w[wv] = x;
        __syncthreads();
        int wvoff = s_carry;
        for (int w = 0; w < wv; w++) wvoff += s_w[w];
        int incl = x + wvoff;
        if (base + t < NATOM) { rowptr[base + t + 1] = incl; cursor[base + t] = incl - v; }
        __syncthreads();
        if (t == 255) s_carry = incl;
        __syncthreads();
    }
}

// pos[e] = dst-sorted position; ssrc[pos[e]] = src[e] (if ssrc != null)
__global__ void pos_kernel(const int* __restrict__ dst, const int* __restrict__ src,
                           int* __restrict__ cursor, int* __restrict__ pos,
                           int* __restrict__ ssrc) {
    for (int e = blockIdx.x * blockDim.x + threadIdx.x; e < NEDGE; e += gridDim.x * blockDim.x) {
        int d = dst[e];
        int p = atomicAdd(&cursor[d], 1);
        pos[e] = p;
        if (ssrc) ssrc[p] = src[e];
    }
}

// ---- weight conversion: w1t[l][n][k<64] = bf16(ew1[l][k][n]) (k>=41 -> 0); w2t[l][n][k] ----
__global__ void wconv_kernel(const float* __restrict__ ew1, const float* __restrict__ ew2,
                             unsigned short* __restrict__ w1t, unsigned short* __restrict__ w2t) {
    int idx = blockIdx.x * 256 + threadIdx.x;
    const int n1 = NL * HD * 64;
    if (idx < n1) {
        int l = idx / (HD * 64); int rem = idx - l * HD * 64; int n = rem >> 6; int k = rem & 63;
        float v = (k < EFD) ? ew1[((size_t)l * EFD + k) * HD + n] : 0.f;
        w1t[idx] = f2b(v);
    } else {
        int j = idx - n1;
        if (j < NL * HD * HD) {
            int l = j / (HD * HD); int rem = j - l * HD * HD; int n = rem >> 7; int k = rem & 127;
            w2t[j] = f2b(ew2[((size_t)l * HD + k) * HD + n]);
        }
    }
}

// ---------------- atom embedding ----------------
__global__ __launch_bounds__(256, 2) void atom_kernel(
    const float* __restrict__ x, const float* __restrict__ w1, const float* __restrict__ b1,
    const float* __restrict__ w2, const float* __restrict__ b2, float* __restrict__ h)
{
    __shared__ float s_x[64 * AFD];
    __shared__ float s_hid[64 * HD];
    const int t = threadIdx.x, cg = t & 31, rg = t >> 5, c4 = cg * 4;
    const int r0 = blockIdx.x * 64;

    for (int i = t; i < 64 * AFD; i += 256) {
        size_t g = (size_t)r0 * AFD + i;
        s_x[i] = (g < (size_t)NATOM * AFD) ? x[g] : 0.f;
    }
    float4 bb1 = *(const float4*)&b1[c4];
    float4 bb2 = *(const float4*)&b2[c4];
    __syncthreads();

    float4 acc[8];
#pragma unroll
    for (int i = 0; i < 8; i++) acc[i] = bb1;
    for (int k = 0; k < AFD; k++) {
        float4 w = *(const float4*)&w1[k * HD + c4];
#pragma unroll
        for (int i = 0; i < 8; i++) {
            float a = s_x[(rg * 8 + i) * AFD + k];
            acc[i].x += a * w.x; acc[i].y += a * w.y; acc[i].z += a * w.z; acc[i].w += a * w.w;
        }
    }
#pragma unroll
    for (int i = 0; i < 8; i++) {
        float4 v = acc[i];
        v.x = silu_f(v.x); v.y = silu_f(v.y); v.z = silu_f(v.z); v.w = silu_f(v.w);
        *(float4*)&s_hid[(rg * 8 + i) * HD + c4] = v;
    }
    __syncthreads();

    float4 o[8];
#pragma unroll
    for (int i = 0; i < 8; i++) o[i] = bb2;
    for (int j = 0; j < HD; j++) {
        float4 w = *(const float4*)&w2[j * HD + c4];
#pragma unroll
        for (int i = 0; i < 8; i++) {
            float a = s_hid[(rg * 8 + i) * HD + j];
            o[i].x += a * w.x; o[i].y += a * w.y; o[i].z += a * w.z; o[i].w += a * w.w;
        }
    }
#pragma unroll
    for (int i = 0; i < 8; i++) {
        int r = r0 + rg * 8 + i;
        if (r < NATOM) *(float4*)&h[(size_t)r * HD + c4] = o[i];
    }
}

// -------- wf_kernel: streaming edge MLP via MFMA, weights in registers --------
// Each wave owns 32 output cols. A-frag: lane l holds A[l&15][(l>>4)*8+j];
// B-frag: B[(l>>4)*8+j][l&15]; D reg r -> D[(l>>4)*4+r][l&15]  (m89-verified)
__global__ __launch_bounds__(256) void wf_kernel(
    const float* __restrict__ edge_attr,
    const unsigned short* __restrict__ w1t, const float* __restrict__ b1,
    const unsigned short* __restrict__ w2t, const float* __restrict__ b2,
    const int* __restrict__ pos, float* __restrict__ wf)
{
    __shared__ __align__(16) unsigned short s_a1[64 * 64];    // 8 KB, swizzled bf16 (K-padded)
    __shared__ __align__(16) unsigned short s_hid[64 * 128];  // 16 KB, swizzled bf16
    __shared__ __align__(16) float s_out[32 * 132];           // 16.9 KB, half-tile transpose
    __shared__ int s_pos[64];

    const int t = threadIdx.x;
    const int wv = t >> 6, lane = t & 63;
    const int lr = lane & 15, lk = lane >> 4;

    // persistent B-fragments (48 VGPRs) + biases, loaded once
    short8 wb1[2][2], wb2[2][4];
    float b1v[2], b2v[2];
#pragma unroll
    for (int nt = 0; nt < 2; nt++) {
        int n = (wv * 2 + nt) * 16 + lr;
        b1v[nt] = b1[n]; b2v[nt] = b2[n];
#pragma unroll
        for (int kk = 0; kk < 2; kk++) wb1[nt][kk] = *(const short8*)&w1t[n * 64 + kk * 32 + lk * 8];
#pragma unroll
        for (int kk = 0; kk < 4; kk++) wb2[nt][kk] = *(const short8*)&w2t[n * 128 + kk * 32 + lk * 8];
    }

    // hoisted staging offsets (tile-invariant): element t+j*256 of the 64x41 slab
    int stg_byte[11];
    bool stg_ok[11];
#pragma unroll
    for (int j = 0; j < 11; j++) {
        int i = t + j * 256;
        stg_ok[j] = (i < 64 * EFD);
        int e = i / EFD, k = i - e * EFD;
        stg_byte[j] = e * 128 + ((2 * k) ^ ((e & 7) << 4));
    }

    // zero-init s_a1: K-pad 41..63 stays zero forever (staging never writes pad slots)
    for (int i = t; i < 64 * 64; i += 256) s_a1[i] = 0;
    __syncthreads();

    const int tc = t & 31, tr8 = t >> 5;
    const int ntiles = NEDGE / 64;
    for (int tile = blockIdx.x; tile < ntiles; tile += gridDim.x) {
        const int e0 = tile * 64;
        if (t < 64) s_pos[t] = pos[e0 + t];
        const float* ea = edge_attr + (size_t)e0 * EFD;
#pragma unroll
        for (int j = 0; j < 11; j++)
            if (stg_ok[j])
                *(unsigned short*)((char*)s_a1 + stg_byte[j]) = f2b(ea[t + j * 256]);
        __syncthreads();

        // ---- GEMM1: hid[64,128] = silu(ea[64,64] @ w1) ---- (this wave: its 32 cols)
        f32x4 acc1[4][2];
#pragma unroll
        for (int rt = 0; rt < 4; rt++) {
            int row = rt * 16 + lr;
            int sw = (row & 7) << 4;
            short8 a0 = *(const short8*)((const char*)s_a1 + row * 128 + ((lk * 16) ^ sw));
            short8 a1 = *(const short8*)((const char*)s_a1 + row * 128 + ((64 + lk * 16) ^ sw));
#pragma unroll
            for (int nt = 0; nt < 2; nt++) {
                f32x4 c = {0.f, 0.f, 0.f, 0.f};
                c = __builtin_amdgcn_mfma_f32_16x16x32_bf16(a0, wb1[nt][0], c, 0, 0, 0);
                c = __builtin_amdgcn_mfma_f32_16x16x32_bf16(a1, wb1[nt][1], c, 0, 0, 0);
                acc1[rt][nt] = c;
            }
        }
        // bias + silu -> bf16 -> s_hid (swizzled)
#pragma unroll
        for (int rt = 0; rt < 4; rt++) {
#pragma unroll
            for (int nt = 0; nt < 2; nt++) {
#pragma unroll
                for (int r = 0; r < 4; r++) {
                    int row = rt * 16 + lk * 4 + r;
                    int col = (wv * 2 + nt) * 16 + lr;
                    float v = silu_f(acc1[rt][nt][r] + b1v[nt]);
                    int byte = row * 256 + ((2 * col) ^ ((row & 7) << 4));
                    *(unsigned short*)((char*)s_hid + byte) = f2b(v);
                }
            }
        }
        __syncthreads();

        // ---- GEMM2: o[64,128] = hid[64,128] @ w2 ---- (this wave: its 32 cols)
        f32x4 acc2[4][2];
#pragma unroll
        for (int rt = 0; rt < 4; rt++) {
            int row = rt * 16 + lr;
            int sw = (row & 7) << 4;
            short8 ha[4];
#pragma unroll
            for (int kk = 0; kk < 4; kk++)
                ha[kk] = *(const short8*)((const char*)s_hid + row * 256 + ((kk * 64 + lk * 16) ^ sw));
#pragma unroll
            for (int nt = 0; nt < 2; nt++) {
                f32x4 c = {0.f, 0.f, 0.f, 0.f};
#pragma unroll
                for (int kk = 0; kk < 4; kk++)
                    c = __builtin_amdgcn_mfma_f32_16x16x32_bf16(ha[kk], wb2[nt][kk], c, 0, 0, 0);
                acc2[rt][nt] = c;
            }
        }

        // epilogue in two 32-row halves through the small s_out buffer
#pragma unroll
        for (int hf = 0; hf < 2; hf++) {
#pragma unroll
            for (int rr = 0; rr < 2; rr++) {
                int rt = hf * 2 + rr;
#pragma unroll
                for (int nt = 0; nt < 2; nt++)
#pragma unroll
                    for (int r = 0; r < 4; r++)
                        s_out[(rr * 16 + lk * 4 + r) * 132 + (wv * 2 + nt) * 16 + lr] =
                            silu_f(acc2[rt][nt][r] + b2v[nt]);
            }
            __syncthreads();
            // coalesced scatter of 32 rows -> dst-sorted positions
#pragma unroll
            for (int i = 0; i < 4; i++) {
                int lrow = tr8 * 4 + i;
                int p = s_pos[hf * 32 + lrow];
                *(float4*)&wf[(size_t)p * HD + tc * 4] = *(const float4*)&s_out[lrow * 132 + tc * 4];
            }
            __syncthreads();
        }
    }
}

// -------- mode-B helper: wf[pos[e]] *= h[src[e]] --------
__global__ void mul_kernel(const float* __restrict__ h, const int* __restrict__ src,
                           const int* __restrict__ pos, float* __restrict__ wf) {
    for (long long idx = (long long)blockIdx.x * 256 + threadIdx.x;
         idx < (long long)NEDGE * 32; idx += (long long)gridDim.x * 256) {
        int e = (int)(idx >> 5), q = (int)(idx & 31);
        int p = pos[e], s = src[e];
        float4 w = *(const float4*)&wf[(size_t)p * HD + q * 4];
        float4 hv = *(const float4*)&h[(size_t)s * HD + q * 4];
        w.x *= hv.x; w.y *= hv.y; w.z *= hv.z; w.w *= hv.w;
        *(float4*)&wf[(size_t)p * HD + q * 4] = w;
    }
}

// -------- node kernel: CSR-sum (fused h-gather multiply), MLP, residual+LN --------
template<bool GATHER>
__global__ __launch_bounds__(256, 2) void node_kernel(
    const float* __restrict__ wfm, const int* __restrict__ rowptr, const int* __restrict__ ssrc,
    const float* __restrict__ h_in,
    const float* __restrict__ w1, const float* __restrict__ b1,
    const float* __restrict__ w2, const float* __restrict__ b2,
    const float* __restrict__ lg, const float* __restrict__ lb,
    float* __restrict__ h_out)
{
    __shared__ float s_in[64 * HD];
    __shared__ float s_hid[64 * HD];
    __shared__ int s_rp[65];
    const int t = threadIdx.x, cg = t & 31, rg = t >> 5, c4 = cg * 4;
    const int r0 = blockIdx.x * 64;

    if (t < 65) {
        int idx = r0 + t;
        if (idx > NATOM) idx = NATOM;
        s_rp[t] = rowptr[idx];
    }
    float4 bb1 = *(const float4*)&b1[c4];
    float4 bb2 = *(const float4*)&b2[c4];
    float4 g4 = *(const float4*)&lg[c4];
    float4 lb4 = *(const float4*)&lb[c4];
    __syncthreads();

    // CSR gather+sum, ILP-4 over edges
#pragma unroll
    for (int i = 0; i < 8; i++) {
        int rr = rg * 8 + i;
        int beg = s_rp[rr], end = s_rp[rr + 1];
        float4 a0 = make_float4(0.f, 0.f, 0.f, 0.f);
        float4 a1 = make_float4(0.f, 0.f, 0.f, 0.f);
        float4 a2 = make_float4(0.f, 0.f, 0.f, 0.f);
        float4 a3 = make_float4(0.f, 0.f, 0.f, 0.f);
        int p = beg;
        for (; p + 3 < end; p += 4) {
            float4 m0 = *(const float4*)&wfm[(size_t)(p + 0) * HD + c4];
            float4 m1 = *(const float4*)&wfm[(size_t)(p + 1) * HD + c4];
            float4 m2 = *(const float4*)&wfm[(size_t)(p + 2) * HD + c4];
            float4 m3 = *(const float4*)&wfm[(size_t)(p + 3) * HD + c4];
            if (GATHER) {
                int s0 = ssrc[p + 0], s1 = ssrc[p + 1], s2 = ssrc[p + 2], s3 = ssrc[p + 3];
                float4 h0 = *(const float4*)&h_in[(size_t)s0 * HD + c4];
                float4 h1 = *(const float4*)&h_in[(size_t)s1 * HD + c4];
                float4 h2 = *(const float4*)&h_in[(size_t)s2 * HD + c4];
                float4 h3 = *(const float4*)&h_in[(size_t)s3 * HD + c4];
                a0.x = fmaf(m0.x, h0.x, a0.x); a0.y = fmaf(m0.y, h0.y, a0.y);
                a0.z = fmaf(m0.z, h0.z, a0.z); a0.w = fmaf(m0.w, h0.w, a0.w);
                a1.x = fmaf(m1.x, h1.x, a1.x); a1.y = fmaf(m1.y, h1.y, a1.y);
                a1.z = fmaf(m1.z, h1.z, a1.z); a1.w = fmaf(m1.w, h1.w, a1.w);
                a2.x = fmaf(m2.x, h2.x, a2.x); a2.y = fmaf(m2.y, h2.y, a2.y);
                a2.z = fmaf(m2.z, h2.z, a2.z); a2.w = fmaf(m2.w, h2.w, a2.w);
                a3.x = fmaf(m3.x, h3.x, a3.x); a3.y = fmaf(m3.y, h3.y, a3.y);
                a3.z = fmaf(m3.z, h3.z, a3.z); a3.w = fmaf(m3.w, h3.w, a3.w);
            } else {
                a0.x += m0.x; a0.y += m0.y; a0.z += m0.z; a0.w += m0.w;
                a1.x += m1.x; a1.y += m1.y; a1.z += m1.z; a1.w += m1.w;
                a2.x += m2.x; a2.y += m2.y; a2.z += m2.z; a2.w += m2.w;
                a3.x += m3.x; a3.y += m3.y; a3.z += m3.z; a3.w += m3.w;
            }
        }
        for (; p < end; p++) {
            float4 m0 = *(const float4*)&wfm[(size_t)p * HD + c4];
            if (GATHER) {
                int s0 = ssrc[p];
                float4 h0 = *(const float4*)&h_in[(size_t)s0 * HD + c4];
                a0.x = fmaf(m0.x, h0.x, a0.x); a0.y = fmaf(m0.y, h0.y, a0.y);
                a0.z = fmaf(m0.z, h0.z, a0.z); a0.w = fmaf(m0.w, h0.w, a0.w);
            } else {
                a0.x += m0.x; a0.y += m0.y; a0.z += m0.z; a0.w += m0.w;
            }
        }
        a0.x += a1.x + a2.x + a3.x; a0.y += a1.y + a2.y + a3.y;
        a0.z += a1.z + a2.z + a3.z; a0.w += a1.w + a2.w + a3.w;
        *(float4*)&s_in[rr * HD + c4] = a0;
    }
    __syncthreads();

    float4 acc[8];
#pragma unroll
    for (int i = 0; i < 8; i++) acc[i] = bb1;
    for (int k = 0; k < HD; k++) {
        float4 w = *(const float4*)&w1[k * HD + c4];
#pragma unroll
        for (int i = 0; i < 8; i++) {
            float a = s_in[(rg * 8 + i) * HD + k];
            acc[i].x += a * w.x; acc[i].y += a * w.y; acc[i].z += a * w.z; acc[i].w += a * w.w;
        }
    }
#pragma unroll
    for (int i = 0; i < 8; i++) {
        float4 v = acc[i];
        v.x = silu_f(v.x); v.y = silu_f(v.y); v.z = silu_f(v.z); v.w = silu_f(v.w);
        *(float4*)&s_hid[(rg * 8 + i) * HD + c4] = v;
    }
    __syncthreads();

    float4 o[8];
#pragma unroll
    for (int i = 0; i < 8; i++) o[i] = bb2;
    for (int j = 0; j < HD; j++) {
        float4 w = *(const float4*)&w2[j * HD + c4];
#pragma unroll
        for (int i = 0; i < 8; i++) {
            float a = s_hid[(rg * 8 + i) * HD + j];
            o[i].x += a * w.x; o[i].y += a * w.y; o[i].z += a * w.z; o[i].w += a * w.w;
        }
    }
#pragma unroll
    for (int i = 0; i < 8; i++) {
        int r = r0 + rg * 8 + i;
        float4 hv = make_float4(0.f, 0.f, 0.f, 0.f);
        if (r < NATOM) hv = *(const float4*)&h_in[(size_t)r * HD + c4];
        float4 v;
        v.x = hv.x + o[i].x; v.y = hv.y + o[i].y; v.z = hv.z + o[i].z; v.w = hv.w + o[i].w;
        float s1 = v.x + v.y + v.z + v.w;
        float s2 = v.x * v.x + v.y * v.y + v.z * v.z + v.w * v.w;
#pragma unroll
        for (int off = 16; off >= 1; off >>= 1) {
            s1 += __shfl_xor(s1, off);
            s2 += __shfl_xor(s2, off);
        }
        float mean = s1 * (1.f / HD);
        float var = s2 * (1.f / HD) - mean * mean;
        float rstd = rsqrtf(var + LNEPS);
        float4 y;
        y.x = (v.x - mean) * rstd * g4.x + lb4.x;
        y.y = (v.y - mean) * rstd * g4.y + lb4.y;
        y.z = (v.z - mean) * rstd * g4.z + lb4.z;
        y.w = (v.w - mean) * rstd * g4.w + lb4.w;
        if (r < NATOM) *(float4*)&h_out[(size_t)r * HD + c4] = y;
    }
}

// -------- pool + head ----------
__global__ __launch_bounds__(128) void head_kernel(
    const float* __restrict__ h, const float* __restrict__ gfeat,
    const float* __restrict__ gw, const float* __restrict__ gb,
    const float* __restrict__ ow1, const float* __restrict__ ob1,
    const float* __restrict__ ow2, const float* __restrict__ ob2,
    const float* __restrict__ ow3, const float* __restrict__ ob3,
    const int* __restrict__ batch, float* __restrict__ out)
{
    __shared__ float comb[2 * HD];
    __shared__ float h1[HD];
    __shared__ float h2[64];
    const int b = blockIdx.x;
    const int c = threadIdx.x;

    int lo = 0, hi = NATOM;
    while (lo < hi) { int m = (lo + hi) >> 1; if (batch[m] < b) lo = m + 1; else hi = m; }
    const int start = lo;
    hi = NATOM;
    while (lo < hi) { int m = (lo + hi) >> 1; if (batch[m] < b + 1) lo = m + 1; else hi = m; }
    const int end = lo;

    float s = 0.f;
    for (int r = start; r < end; r++) s += h[(size_t)r * HD + c];
    float cnt = (float)(end - start);
    if (cnt < 1.f) cnt = 1.f;
    comb[c] = s / cnt;

    float a = gb[c];
    for (int k = 0; k < GFD; k++) a += gfeat[b * GFD + k] * gw[k * HD + c];
    comb[HD + c] = silu_f(a);
    __syncthreads();

    float u = ob1[c];
    for (int j = 0; j < 2 * HD; j++) u += comb[j] * ow1[j * HD + c];
    h1[c] = silu_f(u);
    __syncthreads();

    if (c < 64) {
        float v = ob2[c];
        for (int j = 0; j < HD; j++) v += h1[j] * ow2[j * 64 + c];
        h2[c] = silu_f(v);
    }
    __syncthreads();

    if (c < TOUT) {
        float v = ob3[c];
        for (int j = 0; j < 64; j++) v += h2[j] * ow3[j * TOUT + c];
        out[b * TOUT + c] = v;
    }
}

extern "C" void kernel_launch(void* const* d_in, const int* in_sizes, int n_in,
                              void* d_out, int out_size, void* d_ws, size_t ws_size,
                              hipStream_t stream) {
    const float* x        = (const float*)d_in[0];
    const float* edge_attr= (const float*)d_in[1];
    const float* gfeat    = (const float*)d_in[2];
    const float* ae_w1    = (const float*)d_in[3];
    const float* ae_b1    = (const float*)d_in[4];
    const float* ae_w2    = (const float*)d_in[5];
    const float* ae_b2    = (const float*)d_in[6];
    const float* ew1      = (const float*)d_in[7];
    const float* eb1      = (const float*)d_in[8];
    const float* ew2      = (const float*)d_in[9];
    const float* eb2      = (const float*)d_in[10];
    const float* nw1      = (const float*)d_in[11];
    const float* nb1      = (const float*)d_in[12];
    const float* nw2      = (const float*)d_in[13];
    const float* nb2      = (const float*)d_in[14];
    const float* ln_g     = (const float*)d_in[15];
    const float* ln_b     = (const float*)d_in[16];
    const float* gw       = (const float*)d_in[17];
    const float* gb       = (const float*)d_in[18];
    const float* ow1      = (const float*)d_in[19];
    const float* ob1      = (const float*)d_in[20];
    const float* ow2      = (const float*)d_in[21];
    const float* ob2      = (const float*)d_in[22];
    const float* ow3      = (const float*)d_in[23];
    const float* ob3      = (const float*)d_in[24];
    const int* edge_index = (const int*)d_in[25];
    const int* batch      = (const int*)d_in[26];

    const int* src = edge_index;
    const int* dst = edge_index + NEDGE;
    const int row_blocks = (NATOM + 63) / 64;  // 782

    // workspace: h0 | [h1] | wf | count | rowptr | cursor | pos | [ssrc] | w1t | w2t
    float* h0 = (float*)d_ws;
    size_t fA = (size_t)NATOM * HD * 2 + (size_t)NEDGE * HD;
    size_t intsA = (size_t)NATOM * 3 + 4 + (size_t)NEDGE * 2;
    size_t wele = (size_t)NL * HD * 64 + (size_t)NL * HD * HD;
    size_t needA = fA * 4 + intsA * 4 + wele * 2;

    bool modeA = (ws_size >= needA);

    float* h1   = modeA ? (h0 + (size_t)NATOM * HD) : h0;
    float* wf   = (modeA ? h1 : h0) + (size_t)NATOM * HD;
    int* count  = (int*)(wf + (size_t)NEDGE * HD);
    int* rowptr = count + NATOM;
    int* cursor = rowptr + NATOM + 4;
    int* pos    = cursor + NATOM;
    int* ssrc   = modeA ? (pos + NEDGE) : nullptr;
    unsigned short* w1t = (unsigned short*)(modeA ? (ssrc + NEDGE) : (pos + NEDGE));
    unsigned short* w2t = w1t + NL * HD * 64;

    // ---- prologue: counting sort + weight conversion ----
    hipMemsetAsync(count, 0, NATOM * sizeof(int), stream);
    hist_kernel<<<1024, 256, 0, stream>>>(dst, count);
    scan_kernel<<<1, 256, 0, stream>>>(count, rowptr, cursor);
    pos_kernel<<<1024, 256, 0, stream>>>(dst, src, cursor, pos, ssrc);
    wconv_kernel<<<(NL * HD * 64 + NL * HD * HD + 255) / 256, 256, 0, stream>>>(ew1, ew2, w1t, w2t);

    atom_kernel<<<row_blocks, 256, 0, stream>>>(x, ae_w1, ae_b1, ae_w2, ae_b2, h0);

    const float* cur = h0;
    float* nxt = modeA ? h1 : h0;
    for (int l = 0; l < NL; l++) {
        wf_kernel<<<2048, 256, 0, stream>>>(
            edge_attr,
            w1t + (size_t)l * HD * 64, eb1 + (size_t)l * HD,
            w2t + (size_t)l * HD * HD, eb2 + (size_t)l * HD,
            pos, wf);
        if (modeA) {
            node_kernel<true><<<row_blocks, 256, 0, stream>>>(
                wf, rowptr, ssrc, cur,
                nw1 + (size_t)l * HD * HD, nb1 + (size_t)l * HD,
                nw2 + (size_t)l * HD * HD, nb2 + (size_t)l * HD,
                ln_g + (size_t)l * HD, ln_b + (size_t)l * HD,
                nxt);
            const float* tmp = cur; cur = nxt; nxt = (float*)tmp;
        } else {
            mul_kernel<<<2048, 256, 0, stream>>>(h0, src, pos, wf);
            node_kernel<false><<<row_blocks, 256, 0, stream>>>(
                wf, rowptr, nullptr, h0,
                nw1 + (size_t)l * HD * HD, nb1 + (size_t)l * HD,
                nw2 + (size_t)l * HD * HD, nb2 + (size_t)l * HD,
                ln_g + (size_t)l * HD, ln_b + (size_t)l * HD,
                h0);
        }
    }

    head_kernel<<<NGRAPH, 128, 0, stream>>>(
        cur, gfeat, gw, gb, ow1, ob1, ow2, ob2, ow3, ob3, batch, (float*)d_out);
}

// Round 9
// 1993.803 us; speedup vs baseline: 2.1823x; 1.1074x over previous
//
#include <hip/hip_runtime.h>
#include <math.h>

#define NATOM 50000
#define NEDGE 800000
#define NGRAPH 256
#define HD 128
#define NL 4
#define AFD 108
#define EFD 41
#define GFD 239
#define TOUT 5
#define LNEPS 1e-5f

typedef __attribute__((ext_vector_type(8))) short short8;
typedef __attribute__((ext_vector_type(4))) float f32x4;

// fast silu: v_exp + v_rcp (1-ulp) instead of IEEE divide sequence
__device__ __forceinline__ float silu_f(float v) {
    return v * __builtin_amdgcn_rcpf(1.f + __expf(-v));
}

__device__ __forceinline__ unsigned short f2b(float f) {
    union { float f; unsigned u; } x; x.f = f;
    unsigned r = x.u + 0x7fffu + ((x.u >> 16) & 1u);   // RNE
    return (unsigned short)(r >> 16);
}

// ---------------- CSR build ----------------
__global__ void hist_kernel(const int* __restrict__ dst, int* __restrict__ count) {
    for (int e = blockIdx.x * blockDim.x + threadIdx.x; e < NEDGE; e += gridDim.x * blockDim.x)
        atomicAdd(&count[dst[e]], 1);
}

// single-block scan, 1024 threads (49 iterations over 50k)
__global__ void scan_kernel(const int* __restrict__ count, int* __restrict__ rowptr,
                            int* __restrict__ cursor) {
    __shared__ int s_w[16];
    __shared__ int s_carry;
    const int t = threadIdx.x, lane = t & 63, wv = t >> 6;
    if (t == 0) { s_carry = 0; rowptr[0] = 0; }
    __syncthreads();
    for (int base = 0; base < NATOM; base += 1024) {
        int v = (base + t < NATOM) ? count[base + t] : 0;
        int x = v;
#pragma unroll
        for (int off = 1; off < 64; off <<= 1) {
            int y = __shfl_up(x, off);
            if (lane >= off) x += y;
        }
        if (lane == 63) s_w[wv] = x;
        __syncthreads();
        int wvoff = s_carry;
        for (int w = 0; w < wv; w++) wvoff += s_w[w];
        int incl = x + wvoff;
        if (base + t < NATOM) { rowptr[base + t + 1] = incl; cursor[base + t] = incl - v; }
        __syncthreads();
        if (t == 1023) s_carry = incl;
        __syncthreads();
    }
}

// pos[e] = dst-sorted position; ssrc[pos[e]] = src[e] (if ssrc != null)
__global__ void pos_kernel(const int* __restrict__ dst, const int* __restrict__ src,
                           int* __restrict__ cursor, int* __restrict__ pos,
                           int* __restrict__ ssrc) {
    for (int e = blockIdx.x * blockDim.x + threadIdx.x; e < NEDGE; e += gridDim.x * blockDim.x) {
        int d = dst[e];
        int p = atomicAdd(&cursor[d], 1);
        pos[e] = p;
        if (ssrc) ssrc[p] = src[e];
    }
}

// ---- weight conversion: w1t[l][n][k<64] = bf16(ew1[l][k][n]) (k>=41 -> 0); w2t[l][n][k] ----
__global__ void wconv_kernel(const float* __restrict__ ew1, const float* __restrict__ ew2,
                             unsigned short* __restrict__ w1t, unsigned short* __restrict__ w2t) {
    int idx = blockIdx.x * 256 + threadIdx.x;
    const int n1 = NL * HD * 64;
    if (idx < n1) {
        int l = idx / (HD * 64); int rem = idx - l * HD * 64; int n = rem >> 6; int k = rem & 63;
        float v = (k < EFD) ? ew1[((size_t)l * EFD + k) * HD + n] : 0.f;
        w1t[idx] = f2b(v);
    } else {
        int j = idx - n1;
        if (j < NL * HD * HD) {
            int l = j / (HD * HD); int rem = j - l * HD * HD; int n = rem >> 7; int k = rem & 127;
            w2t[j] = f2b(ew2[((size_t)l * HD + k) * HD + n]);
        }
    }
}

// ---------------- atom embedding ----------------
__global__ __launch_bounds__(256, 2) void atom_kernel(
    const float* __restrict__ x, const float* __restrict__ w1, const float* __restrict__ b1,
    const float* __restrict__ w2, const float* __restrict__ b2, float* __restrict__ h)
{
    __shared__ float s_x[64 * AFD];
    __shared__ float s_hid[64 * HD];
    const int t = threadIdx.x, cg = t & 31, rg = t >> 5, c4 = cg * 4;
    const int r0 = blockIdx.x * 64;

    for (int i = t; i < 64 * AFD; i += 256) {
        size_t g = (size_t)r0 * AFD + i;
        s_x[i] = (g < (size_t)NATOM * AFD) ? x[g] : 0.f;
    }
    float4 bb1 = *(const float4*)&b1[c4];
    float4 bb2 = *(const float4*)&b2[c4];
    __syncthreads();

    float4 acc[8];
#pragma unroll
    for (int i = 0; i < 8; i++) acc[i] = bb1;
    for (int k = 0; k < AFD; k++) {
        float4 w = *(const float4*)&w1[k * HD + c4];
#pragma unroll
        for (int i = 0; i < 8; i++) {
            float a = s_x[(rg * 8 + i) * AFD + k];
            acc[i].x += a * w.x; acc[i].y += a * w.y; acc[i].z += a * w.z; acc[i].w += a * w.w;
        }
    }
#pragma unroll
    for (int i = 0; i < 8; i++) {
        float4 v = acc[i];
        v.x = silu_f(v.x); v.y = silu_f(v.y); v.z = silu_f(v.z); v.w = silu_f(v.w);
        *(float4*)&s_hid[(rg * 8 + i) * HD + c4] = v;
    }
    __syncthreads();

    float4 o[8];
#pragma unroll
    for (int i = 0; i < 8; i++) o[i] = bb2;
    for (int j = 0; j < HD; j++) {
        float4 w = *(const float4*)&w2[j * HD + c4];
#pragma unroll
        for (int i = 0; i < 8; i++) {
            float a = s_hid[(rg * 8 + i) * HD + j];
            o[i].x += a * w.x; o[i].y += a * w.y; o[i].z += a * w.z; o[i].w += a * w.w;
        }
    }
#pragma unroll
    for (int i = 0; i < 8; i++) {
        int r = r0 + rg * 8 + i;
        if (r < NATOM) *(float4*)&h[(size_t)r * HD + c4] = o[i];
    }
}

// -------- wf_kernel: streaming edge MLP via MFMA, weights in registers --------
// Each wave owns 32 output cols. A-frag: lane l holds A[l&15][(l>>4)*8+j];
// B-frag: B[(l>>4)*8+j][l&15]; D reg r -> D[(l>>4)*4+r][l&15]  (m89-verified)
__global__ __launch_bounds__(256) void wf_kernel(
    const float* __restrict__ edge_attr,
    const unsigned short* __restrict__ w1t, const float* __restrict__ b1,
    const unsigned short* __restrict__ w2t, const float* __restrict__ b2,
    const int* __restrict__ pos, float* __restrict__ wf)
{
    __shared__ __align__(16) unsigned short s_a1[64 * 64];    // 8 KB, swizzled bf16 (K-padded)
    __shared__ __align__(16) unsigned short s_hid[64 * 128];  // 16 KB, swizzled bf16
    __shared__ __align__(16) float s_out[16 * 132];           // 8.4 KB, quarter-tile transpose
    __shared__ int s_pos[64];

    const int t = threadIdx.x;
    const int wv = t >> 6, lane = t & 63;
    const int lr = lane & 15, lk = lane >> 4;

    // persistent B-fragments (48 VGPRs) + biases, loaded once
    short8 wb1[2][2], wb2[2][4];
    float b1v[2], b2v[2];
#pragma unroll
    for (int nt = 0; nt < 2; nt++) {
        int n = (wv * 2 + nt) * 16 + lr;
        b1v[nt] = b1[n]; b2v[nt] = b2[n];
#pragma unroll
        for (int kk = 0; kk < 2; kk++) wb1[nt][kk] = *(const short8*)&w1t[n * 64 + kk * 32 + lk * 8];
#pragma unroll
        for (int kk = 0; kk < 4; kk++) wb2[nt][kk] = *(const short8*)&w2t[n * 128 + kk * 32 + lk * 8];
    }

    // hoisted staging offsets (tile-invariant): element t+j*256 of the 64x41 slab
    int stg_byte[11];
    bool stg_ok[11];
#pragma unroll
    for (int j = 0; j < 11; j++) {
        int i = t + j * 256;
        stg_ok[j] = (i < 64 * EFD);
        int e = i / EFD, k = i - e * EFD;
        stg_byte[j] = e * 128 + ((2 * k) ^ ((e & 7) << 4));
    }

    // zero-init s_a1: K-pad 41..63 stays zero forever (staging never writes pad slots)
    for (int i = t; i < 64 * 64; i += 256) s_a1[i] = 0;
    __syncthreads();

    const int tc = t & 31, tr8 = t >> 5;
    const int ntiles = NEDGE / 64;
    for (int tile = blockIdx.x; tile < ntiles; tile += gridDim.x) {
        const int e0 = tile * 64;
        if (t < 64) s_pos[t] = pos[e0 + t];
        const float* ea = edge_attr + (size_t)e0 * EFD;
#pragma unroll
        for (int j = 0; j < 11; j++)
            if (stg_ok[j])
                *(unsigned short*)((char*)s_a1 + stg_byte[j]) = f2b(ea[t + j * 256]);
        __syncthreads();

        // ---- GEMM1: hid[64,128] = silu(ea[64,64] @ w1) ---- (this wave: its 32 cols)
        f32x4 acc1[4][2];
#pragma unroll
        for (int rt = 0; rt < 4; rt++) {
            int row = rt * 16 + lr;
            int sw = (row & 7) << 4;
            short8 a0 = *(const short8*)((const char*)s_a1 + row * 128 + ((lk * 16) ^ sw));
            short8 a1 = *(const short8*)((const char*)s_a1 + row * 128 + ((64 + lk * 16) ^ sw));
#pragma unroll
            for (int nt = 0; nt < 2; nt++) {
                f32x4 c = {0.f, 0.f, 0.f, 0.f};
                c = __builtin_amdgcn_mfma_f32_16x16x32_bf16(a0, wb1[nt][0], c, 0, 0, 0);
                c = __builtin_amdgcn_mfma_f32_16x16x32_bf16(a1, wb1[nt][1], c, 0, 0, 0);
                acc1[rt][nt] = c;
            }
        }
        // bias + silu -> bf16 -> s_hid (swizzled)
#pragma unroll
        for (int rt = 0; rt < 4; rt++) {
#pragma unroll
            for (int nt = 0; nt < 2; nt++) {
#pragma unroll
                for (int r = 0; r < 4; r++) {
                    int row = rt * 16 + lk * 4 + r;
                    int col = (wv * 2 + nt) * 16 + lr;
                    float v = silu_f(acc1[rt][nt][r] + b1v[nt]);
                    int byte = row * 256 + ((2 * col) ^ ((row & 7) << 4));
                    *(unsigned short*)((char*)s_hid + byte) = f2b(v);
                }
            }
        }
        __syncthreads();

        // ---- GEMM2: o[64,128] = hid[64,128] @ w2 ---- (this wave: its 32 cols)
        f32x4 acc2[4][2];
#pragma unroll
        for (int rt = 0; rt < 4; rt++) {
            int row = rt * 16 + lr;
            int sw = (row & 7) << 4;
            short8 ha[4];
#pragma unroll
            for (int kk = 0; kk < 4; kk++)
                ha[kk] = *(const short8*)((const char*)s_hid + row * 256 + ((kk * 64 + lk * 16) ^ sw));
#pragma unroll
            for (int nt = 0; nt < 2; nt++) {
                f32x4 c = {0.f, 0.f, 0.f, 0.f};
#pragma unroll
                for (int kk = 0; kk < 4; kk++)
                    c = __builtin_amdgcn_mfma_f32_16x16x32_bf16(ha[kk], wb2[nt][kk], c, 0, 0, 0);
                acc2[rt][nt] = c;
            }
        }

        // epilogue in four 16-row quarters through the small s_out buffer
#pragma unroll
        for (int hf = 0; hf < 4; hf++) {
#pragma unroll
            for (int nt = 0; nt < 2; nt++)
#pragma unroll
                for (int r = 0; r < 4; r++)
                    s_out[(lk * 4 + r) * 132 + (wv * 2 + nt) * 16 + lr] =
                        silu_f(acc2[hf][nt][r] + b2v[nt]);
            __syncthreads();
            // coalesced scatter of 16 rows -> dst-sorted positions
#pragma unroll
            for (int i = 0; i < 2; i++) {
                int lrow = tr8 * 2 + i;
                int p = s_pos[hf * 16 + lrow];
                *(float4*)&wf[(size_t)p * HD + tc * 4] = *(const float4*)&s_out[lrow * 132 + tc * 4];
            }
            __syncthreads();
        }
    }
}

// -------- mode-B helper: wf[pos[e]] *= h[src[e]] --------
__global__ void mul_kernel(const float* __restrict__ h, const int* __restrict__ src,
                           const int* __restrict__ pos, float* __restrict__ wf) {
    for (long long idx = (long long)blockIdx.x * 256 + threadIdx.x;
         idx < (long long)NEDGE * 32; idx += (long long)gridDim.x * 256) {
        int e = (int)(idx >> 5), q = (int)(idx & 31);
        int p = pos[e], s = src[e];
        float4 w = *(const float4*)&wf[(size_t)p * HD + q * 4];
        float4 hv = *(const float4*)&h[(size_t)s * HD + q * 4];
        w.x *= hv.x; w.y *= hv.y; w.z *= hv.z; w.w *= hv.w;
        *(float4*)&wf[(size_t)p * HD + q * 4] = w;
    }
}

// -------- node kernel: CSR-sum (fused h-gather multiply), MLP, residual+LN --------
// Single 32KB LDS buffer: each 32-thread row-group only touches its own 8 rows,
// so s_in can be overwritten with hid between two barriers. 33 KB -> 4 blocks/CU.
template<bool GATHER>
__global__ __launch_bounds__(256) void node_kernel(
    const float* __restrict__ wfm, const int* __restrict__ rowptr, const int* __restrict__ ssrc,
    const float* __restrict__ h_in,
    const float* __restrict__ w1, const float* __restrict__ b1,
    const float* __restrict__ w2, const float* __restrict__ b2,
    const float* __restrict__ lg, const float* __restrict__ lb,
    float* __restrict__ h_out)
{
    __shared__ float s_buf[64 * HD];
    __shared__ int s_rp[65];
    const int t = threadIdx.x, cg = t & 31, rg = t >> 5, c4 = cg * 4;
    const int r0 = blockIdx.x * 64;

    if (t < 65) {
        int idx = r0 + t;
        if (idx > NATOM) idx = NATOM;
        s_rp[t] = rowptr[idx];
    }
    float4 bb1 = *(const float4*)&b1[c4];
    float4 bb2 = *(const float4*)&b2[c4];
    float4 g4 = *(const float4*)&lg[c4];
    float4 lb4 = *(const float4*)&lb[c4];
    __syncthreads();

    // CSR gather+sum, ILP-4 over edges
#pragma unroll
    for (int i = 0; i < 8; i++) {
        int rr = rg * 8 + i;
        int beg = s_rp[rr], end = s_rp[rr + 1];
        float4 a0 = make_float4(0.f, 0.f, 0.f, 0.f);
        float4 a1 = make_float4(0.f, 0.f, 0.f, 0.f);
        float4 a2 = make_float4(0.f, 0.f, 0.f, 0.f);
        float4 a3 = make_float4(0.f, 0.f, 0.f, 0.f);
        int p = beg;
        for (; p + 3 < end; p += 4) {
            float4 m0 = *(const float4*)&wfm[(size_t)(p + 0) * HD + c4];
            float4 m1 = *(const float4*)&wfm[(size_t)(p + 1) * HD + c4];
            float4 m2 = *(const float4*)&wfm[(size_t)(p + 2) * HD + c4];
            float4 m3 = *(const float4*)&wfm[(size_t)(p + 3) * HD + c4];
            if (GATHER) {
                int s0 = ssrc[p + 0], s1 = ssrc[p + 1], s2 = ssrc[p + 2], s3 = ssrc[p + 3];
                float4 h0 = *(const float4*)&h_in[(size_t)s0 * HD + c4];
                float4 h1 = *(const float4*)&h_in[(size_t)s1 * HD + c4];
                float4 h2 = *(const float4*)&h_in[(size_t)s2 * HD + c4];
                float4 h3 = *(const float4*)&h_in[(size_t)s3 * HD + c4];
                a0.x = fmaf(m0.x, h0.x, a0.x); a0.y = fmaf(m0.y, h0.y, a0.y);
                a0.z = fmaf(m0.z, h0.z, a0.z); a0.w = fmaf(m0.w, h0.w, a0.w);
                a1.x = fmaf(m1.x, h1.x, a1.x); a1.y = fmaf(m1.y, h1.y, a1.y);
                a1.z = fmaf(m1.z, h1.z, a1.z); a1.w = fmaf(m1.w, h1.w, a1.w);
                a2.x = fmaf(m2.x, h2.x, a2.x); a2.y = fmaf(m2.y, h2.y, a2.y);
                a2.z = fmaf(m2.z, h2.z, a2.z); a2.w = fmaf(m2.w, h2.w, a2.w);
                a3.x = fmaf(m3.x, h3.x, a3.x); a3.y = fmaf(m3.y, h3.y, a3.y);
                a3.z = fmaf(m3.z, h3.z, a3.z); a3.w = fmaf(m3.w, h3.w, a3.w);
            } else {
                a0.x += m0.x; a0.y += m0.y; a0.z += m0.z; a0.w += m0.w;
                a1.x += m1.x; a1.y += m1.y; a1.z += m1.z; a1.w += m1.w;
                a2.x += m2.x; a2.y += m2.y; a2.z += m2.z; a2.w += m2.w;
                a3.x += m3.x; a3.y += m3.y; a3.z += m3.z; a3.w += m3.w;
            }
        }
        for (; p < end; p++) {
            float4 m0 = *(const float4*)&wfm[(size_t)p * HD + c4];
            if (GATHER) {
                int s0 = ssrc[p];
                float4 h0 = *(const float4*)&h_in[(size_t)s0 * HD + c4];
                a0.x = fmaf(m0.x, h0.x, a0.x); a0.y = fmaf(m0.y, h0.y, a0.y);
                a0.z = fmaf(m0.z, h0.z, a0.z); a0.w = fmaf(m0.w, h0.w, a0.w);
            } else {
                a0.x += m0.x; a0.y += m0.y; a0.z += m0.z; a0.w += m0.w;
            }
        }
        a0.x += a1.x + a2.x + a3.x; a0.y += a1.y + a2.y + a3.y;
        a0.z += a1.z + a2.z + a3.z; a0.w += a1.w + a2.w + a3.w;
        *(float4*)&s_buf[rr * HD + c4] = a0;
    }
    __syncthreads();

    // GEMM1: read s_buf (agg), accumulate in regs
    float4 acc[8];
#pragma unroll
    for (int i = 0; i < 8; i++) acc[i] = bb1;
    for (int k = 0; k < HD; k++) {
        float4 w = *(const float4*)&w1[k * HD + c4];
#pragma unroll
        for (int i = 0; i < 8; i++) {
            float a = s_buf[(rg * 8 + i) * HD + k];
            acc[i].x += a * w.x; acc[i].y += a * w.y; acc[i].z += a * w.z; acc[i].w += a * w.w;
        }
    }
    __syncthreads();  // all reads of agg complete
#pragma unroll
    for (int i = 0; i < 8; i++) {
        float4 v = acc[i];
        v.x = silu_f(v.x); v.y = silu_f(v.y); v.z = silu_f(v.z); v.w = silu_f(v.w);
        *(float4*)&s_buf[(rg * 8 + i) * HD + c4] = v;   // overwrite with hid
    }
    __syncthreads();

    // GEMM2: read s_buf (hid)
    float4 o[8];
#pragma unroll
    for (int i = 0; i < 8; i++) o[i] = bb2;
    for (int j = 0; j < HD; j++) {
        float4 w = *(const float4*)&w2[j * HD + c4];
#pragma unroll
        for (int i = 0; i < 8; i++) {
            float a = s_buf[(rg * 8 + i) * HD + j];
            o[i].x += a * w.x; o[i].y += a * w.y; o[i].z += a * w.z; o[i].w += a * w.w;
        }
    }
#pragma unroll
    for (int i = 0; i < 8; i++) {
        int r = r0 + rg * 8 + i;
        float4 hv = make_float4(0.f, 0.f, 0.f, 0.f);
        if (r < NATOM) hv = *(const float4*)&h_in[(size_t)r * HD + c4];
        float4 v;
        v.x = hv.x + o[i].x; v.y = hv.y + o[i].y; v.z = hv.z + o[i].z; v.w = hv.w + o[i].w;
        float s1 = v.x + v.y + v.z + v.w;
        float s2 = v.x * v.x + v.y * v.y + v.z * v.z + v.w * v.w;
#pragma unroll
        for (int off = 16; off >= 1; off >>= 1) {
            s1 += __shfl_xor(s1, off);
            s2 += __shfl_xor(s2, off);
        }
        float mean = s1 * (1.f / HD);
        float var = s2 * (1.f / HD) - mean * mean;
        float rstd = rsqrtf(var + LNEPS);
        float4 y;
        y.x = (v.x - mean) * rstd * g4.x + lb4.x;
        y.y = (v.y - mean) * rstd * g4.y + lb4.y;
        y.z = (v.z - mean) * rstd * g4.z + lb4.z;
        y.w = (v.w - mean) * rstd * g4.w + lb4.w;
        if (r < NATOM) *(float4*)&h_out[(size_t)r * HD + c4] = y;
    }
}

// -------- pool + head ----------
__global__ __launch_bounds__(128) void head_kernel(
    const float* __restrict__ h, const float* __restrict__ gfeat,
    const float* __restrict__ gw, const float* __restrict__ gb,
    const float* __restrict__ ow1, const float* __restrict__ ob1,
    const float* __restrict__ ow2, const float* __restrict__ ob2,
    const float* __restrict__ ow3, const float* __restrict__ ob3,
    const int* __restrict__ batch, float* __restrict__ out)
{
    __shared__ float comb[2 * HD];
    __shared__ float h1[HD];
    __shared__ float h2[64];
    const int b = blockIdx.x;
    const int c = threadIdx.x;

    int lo = 0, hi = NATOM;
    while (lo < hi) { int m = (lo + hi) >> 1; if (batch[m] < b) lo = m + 1; else hi = m; }
    const int start = lo;
    hi = NATOM;
    while (lo < hi) { int m = (lo + hi) >> 1; if (batch[m] < b + 1) lo = m + 1; else hi = m; }
    const int end = lo;

    // pool with ILP-4
    float s0 = 0.f, s1 = 0.f, s2 = 0.f, s3 = 0.f;
    int r = start;
    for (; r + 3 < end; r += 4) {
        s0 += h[(size_t)(r + 0) * HD + c];
        s1 += h[(size_t)(r + 1) * HD + c];
        s2 += h[(size_t)(r + 2) * HD + c];
        s3 += h[(size_t)(r + 3) * HD + c];
    }
    for (; r < end; r++) s0 += h[(size_t)r * HD + c];
    float s = (s0 + s1) + (s2 + s3);
    float cnt = (float)(end - start);
    if (cnt < 1.f) cnt = 1.f;
    comb[c] = s / cnt;

    float a = gb[c];
    for (int k = 0; k < GFD; k++) a += gfeat[b * GFD + k] * gw[k * HD + c];
    comb[HD + c] = silu_f(a);
    __syncthreads();

    float u = ob1[c];
    for (int j = 0; j < 2 * HD; j++) u += comb[j] * ow1[j * HD + c];
    h1[c] = silu_f(u);
    __syncthreads();

    if (c < 64) {
        float v = ob2[c];
        for (int j = 0; j < HD; j++) v += h1[j] * ow2[j * 64 + c];
        h2[c] = silu_f(v);
    }
    __syncthreads();

    if (c < TOUT) {
        float v = ob3[c];
        for (int j = 0; j < 64; j++) v += h2[j] * ow3[j * TOUT + c];
        out[b * TOUT + c] = v;
    }
}

extern "C" void kernel_launch(void* const* d_in, const int* in_sizes, int n_in,
                              void* d_out, int out_size, void* d_ws, size_t ws_size,
                              hipStream_t stream) {
    const float* x        = (const float*)d_in[0];
    const float* edge_attr= (const float*)d_in[1];
    const float* gfeat    = (const float*)d_in[2];
    const float* ae_w1    = (const float*)d_in[3];
    const float* ae_b1    = (const float*)d_in[4];
    const float* ae_w2    = (const float*)d_in[5];
    const float* ae_b2    = (const float*)d_in[6];
    const float* ew1      = (const float*)d_in[7];
    const float* eb1      = (const float*)d_in[8];
    const float* ew2      = (const float*)d_in[9];
    const float* eb2      = (const float*)d_in[10];
    const float* nw1      = (const float*)d_in[11];
    const float* nb1      = (const float*)d_in[12];
    const float* nw2      = (const float*)d_in[13];
    const float* nb2      = (const float*)d_in[14];
    const float* ln_g     = (const float*)d_in[15];
    const float* ln_b     = (const float*)d_in[16];
    const float* gw       = (const float*)d_in[17];
    const float* gb       = (const float*)d_in[18];
    const float* ow1      = (const float*)d_in[19];
    const float* ob1      = (const float*)d_in[20];
    const float* ow2      = (const float*)d_in[21];
    const float* ob2      = (const float*)d_in[22];
    const float* ow3      = (const float*)d_in[23];
    const float* ob3      = (const float*)d_in[24];
    const int* edge_index = (const int*)d_in[25];
    const int* batch      = (const int*)d_in[26];

    const int* src = edge_index;
    const int* dst = edge_index + NEDGE;
    const int row_blocks = (NATOM + 63) / 64;  // 782

    // workspace: h0 | [h1] | wf | count | rowptr | cursor | pos | [ssrc] | w1t | w2t
    float* h0 = (float*)d_ws;
    size_t fA = (size_t)NATOM * HD * 2 + (size_t)NEDGE * HD;
    size_t intsA = (size_t)NATOM * 3 + 4 + (size_t)NEDGE * 2;
    size_t wele = (size_t)NL * HD * 64 + (size_t)NL * HD * HD;
    size_t needA = fA * 4 + intsA * 4 + wele * 2;

    bool modeA = (ws_size >= needA);

    float* h1   = modeA ? (h0 + (size_t)NATOM * HD) : h0;
    float* wf   = (modeA ? h1 : h0) + (size_t)NATOM * HD;
    int* count  = (int*)(wf + (size_t)NEDGE * HD);
    int* rowptr = count + NATOM;
    int* cursor = rowptr + NATOM + 4;
    int* pos    = cursor + NATOM;
    int* ssrc   = modeA ? (pos + NEDGE) : nullptr;
    unsigned short* w1t = (unsigned short*)(modeA ? (ssrc + NEDGE) : (pos + NEDGE));
    unsigned short* w2t = w1t + NL * HD * 64;

    // ---- prologue: counting sort + weight conversion ----
    hipMemsetAsync(count, 0, NATOM * sizeof(int), stream);
    hist_kernel<<<1024, 256, 0, stream>>>(dst, count);
    scan_kernel<<<1, 1024, 0, stream>>>(count, rowptr, cursor);
    pos_kernel<<<1024, 256, 0, stream>>>(dst, src, cursor, pos, ssrc);
    wconv_kernel<<<(NL * HD * 64 + NL * HD * HD + 255) / 256, 256, 0, stream>>>(ew1, ew2, w1t, w2t);

    atom_kernel<<<row_blocks, 256, 0, stream>>>(x, ae_w1, ae_b1, ae_w2, ae_b2, h0);

    const float* cur = h0;
    float* nxt = modeA ? h1 : h0;
    for (int l = 0; l < NL; l++) {
        wf_kernel<<<2048, 256, 0, stream>>>(
            edge_attr,
            w1t + (size_t)l * HD * 64, eb1 + (size_t)l * HD,
            w2t + (size_t)l * HD * HD, eb2 + (size_t)l * HD,
            pos, wf);
        if (modeA) {
            node_kernel<true><<<row_blocks, 256, 0, stream>>>(
                wf, rowptr, ssrc, cur,
                nw1 + (size_t)l * HD * HD, nb1 + (size_t)l * HD,
                nw2 + (size_t)l * HD * HD, nb2 + (size_t)l * HD,
                ln_g + (size_t)l * HD, ln_b + (size_t)l * HD,
                nxt);
            const float* tmp = cur; cur = nxt; nxt = (float*)tmp;
        } else {
            mul_kernel<<<2048, 256, 0, stream>>>(h0, src, pos, wf);
            node_kernel<false><<<row_blocks, 256, 0, stream>>>(
                wf, rowptr, nullptr, h0,
                nw1 + (size_t)l * HD * HD, nb1 + (size_t)l * HD,
                nw2 + (size_t)l * HD * HD, nb2 + (size_t)l * HD,
                ln_g + (size_t)l * HD, ln_b + (size_t)l * HD,
                h0);
        }
    }

    head_kernel<<<NGRAPH, 128, 0, stream>>>(
        cur, gfeat, gw, gb, ow1, ob1, ow2, ob2, ow3, ob3, batch, (float*)d_out);
}